// Round 3
// baseline (506.412 us; speedup 1.0000x reference)
//
#include <hip/hip_runtime.h>
#include <hip/hip_bf16.h>
#include <math.h>

#define BB 8
#define NN 128
#define HH 128
#define NHD 4
#define DHD 32
#define LAY 4
#define EPSV 1e-5f

typedef __hip_bfloat16 bf16;
typedef unsigned short ushortt;
typedef short bf16x8 __attribute__((ext_vector_type(8)));
typedef float f32x4 __attribute__((ext_vector_type(4)));

__device__ __forceinline__ float b2f(bf16 x){ return __bfloat162float(x); }
__device__ __forceinline__ bf16 f2b(float x){ return __float2bfloat16(x); }
__device__ __forceinline__ float us2f(ushortt u){ return __uint_as_float(((unsigned)u)<<16); }
__device__ __forceinline__ ushortt f2us(float x){ bf16 b=__float2bfloat16(x); return *(ushortt*)&b; }
__device__ __forceinline__ float gelu_f(float x){ return 0.5f*x*(1.0f+erff(x*0.7071067811865476f)); }
// fast tanh-gelu — h-path serial loops only (k_edge); measured win there (r13)
__device__ __forceinline__ float gelu_h(float x){
  float t = 0.7978845608028654f*x*(1.0f + 0.044715f*x*x);
  float e = __expf(2.0f*t);
  float th = 1.0f - 2.0f/(e + 1.0f);
  return 0.5f*x*(1.0f + th);
}
// branch-free A&S 7.1.26 erf (|err| <= 1.5e-7) — ~16 VALU vs ocml erff's ~40+divergence.
__device__ __forceinline__ float erf_fast(float x){
  float ax = fabsf(x);
  float t = __builtin_amdgcn_rcpf(__builtin_fmaf(0.3275911f, ax, 1.0f));
  float p = __builtin_fmaf(1.061405429f, t, -1.453152027f);
  p = __builtin_fmaf(p, t, 1.421413741f);
  p = __builtin_fmaf(p, t, -0.284496736f);
  p = __builtin_fmaf(p, t, 0.254829592f);
  p = p*t;
  float e = __expf(-ax*ax);
  float y = __builtin_fmaf(-p, e, 1.0f);
  return __builtin_copysignf(y, x);
}
__device__ __forceinline__ float gelu_fe(float x){
  return 0.5f*x*(1.0f + erf_fast(x*0.7071067811865476f));
}

// ---------------- prep: bf16 weights, transposes, bondW (all layers), xf init ----------------

__global__ __launch_bounds__(256) void k_prep(const float* __restrict__ fe2W,
    const float* __restrict__ preW, const float* __restrict__ eigW,
    const float* __restrict__ qkvW, const float* __restrict__ outW,
    const float* __restrict__ ffn1W, const float* __restrict__ ffn2W,
    const float* __restrict__ f1W, const float* __restrict__ f2W,
    const float* __restrict__ aemb, const int* __restrict__ nf,
    const float* __restrict__ bemb, const float* __restrict__ preb,
    ushortt* __restrict__ wbf, float* __restrict__ gs, float* __restrict__ xf0,
    float* __restrict__ eigWT, float* __restrict__ qkvWT, float* __restrict__ outWT,
    float* __restrict__ ffn1WT, float* __restrict__ ffn2WT,
    float* __restrict__ f1WT, float* __restrict__ f2WT,
    float* __restrict__ bondWall){
  int idx = blockIdx.x*256 + threadIdx.x;    // grid covers 131072
  if (idx < 8192) gs[idx] = 0.f;             // 4 layers x 4 banks x 512
  if (idx < 81920){
    float v = (idx < 16384) ? fe2W[idx] : preW[idx - 16384];
    wbf[idx] = f2us(v);
  }
  if (idx < 131072){
    int node = idx >> 7, h2 = idx & 127;
    xf0[idx] = aemb[nf[node]*HH + h2];
  }
  if (idx < 16512){ int o = idx/129, kq = idx - o*129; eigWT[kq*128+o] = eigW[idx]; }
  if (idx < 49152){ int o = idx>>7, m = idx&127; qkvWT[m*384+o] = qkvW[idx]; }
  if (idx < 16384){ int o = idx>>7, m = idx&127;
    outWT[m*128+o]  = outW[idx];
    ffn1WT[m*128+o] = ffn1W[idx];
    ffn2WT[m*128+o] = ffn2W[idx];
  }
  if (idx < 65536){ int l = idx>>14, r = idx&16383; int o = r>>7, m = r&127;
    f1WT[l*16384 + m*128+o] = f1W[idx];
    f2WT[l*16384 + m*128+o] = f2W[idx];
  }
  if (idx < 5120){   // bondW for all 4 layers: bond_emb @ preW[l]^T + preb[l]
    int l = idx / 1280; int r = idx - l*1280; int e2 = r >> 7; int hcol = r & 127;
    const float* br = bemb + e2*128;
    const float* wr = preW + l*16384 + hcol*128;
    float a0=preb[l*128+hcol], a1=0.f, a2=0.f, a3=0.f;
    for (int m=0;m<128;m+=4){
      a0 += br[m]*wr[m];   a1 += br[m+1]*wr[m+1];
      a2 += br[m+2]*wr[m+2]; a3 += br[m+3]*wr[m+3];
    }
    bondWall[idx] = (a0+a1)+(a2+a3);
  }
}

// ---------------- front end (all f32 — precision-critical for new_e) ----------------
// serial FMA chains split 4-way: hipcc can't reassociate f32 adds, so the naive
// 128-long chains were 4cyc/FMA dependency stalls at 2 waves/SIMD occupancy.

__global__ void k_fe_a(const float* __restrict__ e, const float* __restrict__ eigWT,
                       const float* __restrict__ eigb, const float* __restrict__ g,
                       const float* __restrict__ bt, const float* __restrict__ qkvWT,
                       const float* __restrict__ qkvb,
                       float* __restrict__ eigout, float* __restrict__ q,
                       float* __restrict__ kT, float* __restrict__ v){
  int row = blockIdx.x; int tid = threadIdx.x;
  int b = row >> 7, n = row & 127;
  __shared__ float ee[129]; __shared__ float buf[128]; __shared__ float xm[128];
  float ev = e[row];
  if (tid < 64){
    float dv = expf(-0.1439115683121279f * (float)tid);
    float pe = ev * 100.0f * dv;
    ee[1+tid] = sinf(pe);
    ee[65+tid] = cosf(pe);
  }
  if (tid == 0) ee[0] = ev;
  __syncthreads();
  float a0=eigb[tid], a1=0.f, a2=0.f, a3=0.f;
  for (int k2=0;k2<128;k2+=4){
    a0 += ee[k2]*eigWT[k2*128+tid];
    a1 += ee[k2+1]*eigWT[(k2+1)*128+tid];
    a2 += ee[k2+2]*eigWT[(k2+2)*128+tid];
    a3 += ee[k2+3]*eigWT[(k2+3)*128+tid];
  }
  a0 += ee[128]*eigWT[128*128+tid];
  float x = (a0+a1)+(a2+a3);
  eigout[row*HH+tid] = x;
  buf[tid]=x; __syncthreads();
  for (int s2=64;s2>0;s2>>=1){ if(tid<s2) buf[tid]+=buf[tid+s2]; __syncthreads(); }
  float mean = buf[0]*(1.0f/128.0f); __syncthreads();
  float d = x-mean; buf[tid]=d*d; __syncthreads();
  for (int s2=64;s2>0;s2>>=1){ if(tid<s2) buf[tid]+=buf[tid+s2]; __syncthreads(); }
  float var = buf[0]*(1.0f/128.0f);
  xm[tid] = d*rsqrtf(var+EPSV)*g[tid]+bt[tid];
  __syncthreads();
  #pragma unroll
  for (int s3=0;s3<3;s3++){
    const float* wt = qkvWT + s3*HH + tid;
    float q0=qkvb[s3*HH+tid], q1=0.f, q2=0.f, q3=0.f;
    for (int m=0;m<128;m+=4){
      q0 += xm[m]*wt[m*384];
      q1 += xm[m+1]*wt[(m+1)*384];
      q2 += xm[m+2]*wt[(m+2)*384];
      q3 += xm[m+3]*wt[(m+3)*384];
    }
    float acc = (q0+q1)+(q2+q3);
    if (s3==0) q[row*HH+tid]=acc;
    else if (s3==1) kT[b*16384 + tid*128 + n]=acc;
    else v[row*HH+tid]=acc;
  }
}

__global__ void k_attn(const float* __restrict__ q, const float* __restrict__ kT,
                       const int* __restrict__ length,
                       float* __restrict__ attnf, float* __restrict__ outp){
  int bx = blockIdx.x;
  int qi = bx & 127, hd = (bx>>7)&3, b = bx>>9;
  int tid = threadIdx.x;
  int len = length[b];
  __shared__ float qv[DHD]; __shared__ float red[128];
  if (tid < DHD) qv[tid] = q[(b*NN+qi)*HH + hd*DHD + tid];
  __syncthreads();
  float s = -1e30f;
  if (tid < len){
    const float* kr = kT + b*16384 + hd*DHD*128 + tid;
    float c0=0.f,c1=0.f,c2=0.f,c3=0.f;
    for (int d2=0; d2<DHD; d2+=4){
      c0 += qv[d2]*kr[d2*128];
      c1 += qv[d2+1]*kr[(d2+1)*128];
      c2 += qv[d2+2]*kr[(d2+2)*128];
      c3 += qv[d2+3]*kr[(d2+3)*128];
    }
    s = ((c0+c1)+(c2+c3)) * 0.17677669529663687f;
  }
  red[tid]=s; __syncthreads();
  for (int st=64;st>0;st>>=1){ if(tid<st) red[tid]=fmaxf(red[tid],red[tid+st]); __syncthreads(); }
  float mx = red[0]; __syncthreads();
  float p = (tid<len)? expf(s-mx):0.0f;
  red[tid]=p; __syncthreads();
  for (int st=64;st>0;st>>=1){ if(tid<st) red[tid]+=red[tid+st]; __syncthreads(); }
  float a = p / red[0];
  int idx = ((b*NHD+hd)*NN+qi)*NN+tid;
  attnf[idx]=a;
  outp[4104 + idx]=a;
}

__global__ void k_fe_c(const float* __restrict__ attnf, const float* __restrict__ v,
                       const float* __restrict__ outWT, const float* __restrict__ outb,
                       const float* __restrict__ fng, const float* __restrict__ fnb,
                       const float* __restrict__ w1T, const float* __restrict__ b1,
                       const float* __restrict__ w2T, const float* __restrict__ b2,
                       float* __restrict__ eig){
  int row = blockIdx.x; int b = row>>7, qi = row&127;
  int tid = threadIdx.x;
  __shared__ float c[128]; __shared__ float buf[128]; __shared__ float xm[128]; __shared__ float tt[128];
  int hd = tid>>5;
  const float* ar = attnf + ((b*NHD+hd)*NN+qi)*NN;
  float c0=0.f,c1=0.f,c2=0.f,c3=0.f;
  for (int j=0;j<NN;j+=4){
    c0 += ar[j]*v[(b*NN+j)*HH+tid];
    c1 += ar[j+1]*v[(b*NN+j+1)*HH+tid];
    c2 += ar[j+2]*v[(b*NN+j+2)*HH+tid];
    c3 += ar[j+3]*v[(b*NN+j+3)*HH+tid];
  }
  c[tid]=(c0+c1)+(c2+c3); __syncthreads();
  float o0=outb[tid], o1=0.f, o2=0.f, o3=0.f;
  for (int m=0;m<128;m+=4){
    o0 += c[m]*outWT[m*128+tid];
    o1 += c[m+1]*outWT[(m+1)*128+tid];
    o2 += c[m+2]*outWT[(m+2)*128+tid];
    o3 += c[m+3]*outWT[(m+3)*128+tid];
  }
  float x = eig[row*HH+tid] + (o0+o1)+(o2+o3);
  buf[tid]=x; __syncthreads();
  for (int s2=64;s2>0;s2>>=1){ if(tid<s2) buf[tid]+=buf[tid+s2]; __syncthreads(); }
  float mean=buf[0]*(1.f/128.f); __syncthreads();
  float d=x-mean; buf[tid]=d*d; __syncthreads();
  for (int s2=64;s2>0;s2>>=1){ if(tid<s2) buf[tid]+=buf[tid+s2]; __syncthreads(); }
  float var=buf[0]*(1.f/128.f);
  xm[tid]=d*rsqrtf(var+EPSV)*fng[tid]+fnb[tid];
  __syncthreads();
  float f0=b1[tid], f1=0.f, f2=0.f, f3=0.f;
  for (int m=0;m<128;m+=4){
    f0 += xm[m]*w1T[m*128+tid];
    f1 += xm[m+1]*w1T[(m+1)*128+tid];
    f2 += xm[m+2]*w1T[(m+2)*128+tid];
    f3 += xm[m+3]*w1T[(m+3)*128+tid];
  }
  tt[tid]=gelu_f((f0+f1)+(f2+f3)); __syncthreads();
  float g0=b2[tid], g1=0.f, g2=0.f, g3=0.f;
  for (int m=0;m<128;m+=4){
    g0 += tt[m]*w2T[m*128+tid];
    g1 += tt[m+1]*w2T[(m+1)*128+tid];
    g2 += tt[m+2]*w2T[(m+2)*128+tid];
    g3 += tt[m+3]*w2T[(m+3)*128+tid];
  }
  eig[row*HH+tid]=x+(g0+g1)+(g2+g3);
}

__global__ void k_dec(const float* __restrict__ eig, const float* dW, const float* db,
                      float* __restrict__ newe, float* __restrict__ outp){
  int b = blockIdx.x, n = threadIdx.x;
  __shared__ float w[NHD*HH];
  for (int i=n;i<NHD*HH;i+=128) w[i]=dW[i];
  __syncthreads();
  float acc[NHD], acc2[NHD];
  #pragma unroll
  for (int kk=0;kk<NHD;kk++){ acc[kk]=db[kk]; acc2[kk]=0.f; }
  const float* er = eig + (b*NN+n)*HH;
  for (int h2=0;h2<64;h2++){
    float ev = er[h2], ev2 = er[h2+64];
    #pragma unroll
    for (int kk=0;kk<NHD;kk++){
      acc[kk]+=ev*w[kk*HH+h2];
      acc2[kk]+=ev2*w[kk*HH+h2+64];
    }
  }
  #pragma unroll
  for (int kk=0;kk<NHD;kk++){
    int idx=(b*NHD+kk)*NN+n; float vv=acc[kk]+acc2[kk];
    newe[idx]=vv;
    outp[8 + idx]=vv;
  }
}

// ---------------- bases ----------------

// filt[b][n][p][k] only consumed for n<len, p<len (via k_fe2 -> k_edge) — skip dead tiles
__global__ void k_filters(const float* __restrict__ u, const float* __restrict__ newe,
                          const int* __restrict__ length, float* __restrict__ filt){
  int b = blockIdx.x, n0 = blockIdx.y*16, p0 = blockIdx.z*16;
  int len = length[b];
  if (n0 >= len || p0 >= len) return;   // block-uniform: output never read
  int tx = threadIdx.x, ty = threadIdx.y; int tid = ty*16+tx;
  __shared__ float un[16][17], upt[16][17], wk[4][16];
  float acc[4]={0.f,0.f,0.f,0.f}, accB[4]={0.f,0.f,0.f,0.f};
  for (int mt=0; mt<8; mt++){
    __syncthreads();
    un[ty][tx]  = u[(b*NN+n0+ty)*NN + mt*16+tx];
    upt[tx][ty] = u[(b*NN+p0+ty)*NN + mt*16+tx];
    if (tid<64) wk[tid>>4][tid&15] = newe[(b*NHD+(tid>>4))*NN + mt*16 + (tid&15)];
    __syncthreads();
    #pragma unroll
    for (int mm=0;mm<16;mm+=2){
      float pr0 = un[ty][mm]*upt[mm][tx];
      float pr1 = un[ty][mm+1]*upt[mm+1][tx];
      #pragma unroll
      for (int kk=0;kk<4;kk++){
        acc[kk]  += pr0*wk[kk][mm];
        accB[kk] += pr1*wk[kk][mm+1];
      }
    }
  }
  float4 o; o.x=acc[0]+accB[0];o.y=acc[1]+accB[1];o.z=acc[2]+accB[2];o.w=acc[3]+accB[3];
  *(float4*)&filt[((b*NN+n0+ty)*NN+p0+tx)*4] = o;
}

// bases: LDS-staged fe2 weights; fast erf; length-masked
__global__ __launch_bounds__(256) void k_fe2(const float* __restrict__ filt,
    const float* __restrict__ w1g, const float* __restrict__ b1g,
    const ushortt* __restrict__ w2bf, const float* __restrict__ b2g,
    const int* __restrict__ length,
    bf16* __restrict__ bases){
  int blk = blockIdx.x;
  int bi = blk >> 1;            // b*128 + n
  int r0 = (blk & 1)*64;
  int b = bi >> 7;
  int nloc = bi & 127;
  int len = length[b];
  if (nloc >= len || r0 >= len) return;   // block-uniform: whole output slab unused
  int tid = threadIdx.x;
  int lane = tid & 63, w = tid >> 6, quad = lane >> 4, l15 = lane & 15;
  // hoist the long-latency filt load above staging so HBM latency hides under the copy
  int pr = r0 + w*16 + l15;                 // A row (m index) this lane feeds
  float4 f4 = ((const float4*)filt)[bi*128 + pr];
  __shared__ alignas(16) ushortt sW2[128*136];   // 34816 B; reused as sT[64][132] later
  __shared__ float w1p[128*8];                    // rows: {b1, w0..w4, pad, pad}
  __shared__ float b2s[128];
  for (int idx = tid; idx < 2048; idx += 256){    // 32KB weight copy, 16B chunks
    int r = idx >> 4, cb = idx & 15;
    *(uint4*)&sW2[r*136 + cb*8] = *(const uint4*)&w2bf[r*128 + cb*8];
  }
  for (int idx = tid; idx < 1024; idx += 256){
    int r = idx >> 3, c = idx & 7;
    w1p[idx] = (c==0) ? b1g[r] : (c<=5 ? w1g[r*5 + c-1] : 0.f);
  }
  if (tid < 128) b2s[tid] = b2g[tid];
  __syncthreads();
  // wave w owns rows [r0+16w, r0+16w+16); rows >= len may see uninit filt — garbage
  // stays confined to that MFMA output row (A-row == C-row) and is never stored.
  bool wact = (r0 + w*16) < len;
  f32x4 acc[8];
  #pragma unroll
  for (int nt=0;nt<8;nt++) acc[nt] = (f32x4){0.f,0.f,0.f,0.f};
  if (wact){
    float dg = (pr == nloc) ? 1.0f : 0.0f;
    for (int kk = 0; kk < 128; kk += 32){
      bf16x8 af;
      #pragma unroll
      for (int j=0;j<8;j++){
        int m = kk + quad*8 + j;
        const float4 wa = *(const float4*)&w1p[m*8];     // b1, w0, w1, w2
        const float2 wb = *(const float2*)&w1p[m*8+4];   // w3, w4
        float a = wa.x + wa.y*dg + wa.z*f4.x + wa.w*f4.y + wb.x*f4.z + wb.y*f4.w;
        af[j] = (short)f2us(gelu_fe(a));
      }
      #pragma unroll
      for (int nt=0;nt<8;nt++){
        bf16x8 bfr = *(const bf16x8*)&sW2[(nt*16+l15)*136 + kk + quad*8];
        acc[nt] = __builtin_amdgcn_mfma_f32_16x16x32_bf16(af, bfr, acc[nt], 0, 0, 0);
      }
    }
  }
  __syncthreads();              // all sW2 reads complete -> safe to reuse as sT
  ushortt* sT = sW2;
  if (wact){
    #pragma unroll
    for (int nt=0;nt<8;nt++){
      int h = nt*16 + l15;
      float bb = b2s[h];
      #pragma unroll
      for (int reg=0;reg<4;reg++){
        int lr = w*16 + quad*4 + reg;
        sT[lr*132 + h] = f2us(gelu_fe(acc[nt][reg] + bb));
      }
    }
  }
  __syncthreads();
  int rmax = len - r0; if (rmax > 64) rmax = 64;   // only rows i<len are ever read
  ushort4* gout = (ushort4*)(bases + (size_t)bi*16384 + r0*128);
  for (int idx = tid; idx < rmax*32; idx += 256){
    int row = idx >> 5, seg = idx & 31;
    gout[idx] = *(const ushort4*)&sT[row*132 + seg*4];
  }
}

// ---------------- message passing ----------------
// BN stats are 4-way banked: gstat layout per layer = [bank(4)][512] where
// 512 = gsum1[128] gsq1[128] gsum2[128] gsq2[128]; 64-way (was 256) atomic
// contention per address; consumers sum the 4 banks.

// per-layer (32 blocks): fused BN2-apply of previous layer; xfW = xfB @ preW^T (MFMA)
__global__ __launch_bounds__(256) void k_xwl2(const float* __restrict__ xfprev,
    const float* __restrict__ t2, const float* __restrict__ statp,
    const float* __restrict__ g2p,
    const float* __restrict__ bb2p, const int* __restrict__ length, int prevapply,
    const ushortt* __restrict__ wbfl, float* __restrict__ xfB,
    float* __restrict__ xfW){
  int blk = blockIdx.x;
  int b = blk >> 2, rq = blk & 3;
  int tid = threadIdx.x;
  int lane = tid & 63, w = tid >> 6, quad = lane >> 4, l15 = lane & 15;
  __shared__ alignas(16) ushortt sA[32*136];
  __shared__ float smu[128], sistd[128], sg[128], sbb[128];
  if (prevapply && tid < 128){
    float cnt = 0.f;
    for (int q2=0;q2<BB;q2++) cnt += (float)length[q2];
    float su = (statp[256+tid]+statp[512+256+tid])+(statp[1024+256+tid]+statp[1536+256+tid]);
    float sq = (statp[384+tid]+statp[512+384+tid])+(statp[1024+384+tid]+statp[1536+384+tid]);
    float mu = su/cnt;
    float var = sq/cnt - mu*mu;
    smu[tid]=mu; sistd[tid]=rsqrtf(fmaxf(var,0.0f)+EPSV);
    sg[tid]=g2p[tid]; sbb[tid]=bb2p[tid];
  }
  __syncthreads();
  for (int idx = tid; idx < 1024; idx += 256){
    int r = idx >> 5, c = idx & 31;
    int gr = b*128 + rq*32 + r;
    float4 xv = ((const float4*)xfprev)[gr*32 + c];
    if (prevapply){
      float4 tv = ((const float4*)t2)[gr*32 + c];
      int f0 = c*4;
      xv.x += fmaxf((tv.x-smu[f0+0])*sistd[f0+0]*sg[f0+0]+sbb[f0+0], 0.f);
      xv.y += fmaxf((tv.y-smu[f0+1])*sistd[f0+1]*sg[f0+1]+sbb[f0+1], 0.f);
      xv.z += fmaxf((tv.z-smu[f0+2])*sistd[f0+2]*sg[f0+2]+sbb[f0+2], 0.f);
      xv.w += fmaxf((tv.w-smu[f0+3])*sistd[f0+3]*sg[f0+3]+sbb[f0+3], 0.f);
      ((float4*)xfB)[gr*32 + c] = xv;
    }
    ushort4 o;
    o.x=f2us(xv.x); o.y=f2us(xv.y); o.z=f2us(xv.z); o.w=f2us(xv.w);
    *(ushort4*)&sA[r*136 + c*4] = o;
  }
  __syncthreads();
  f32x4 acc[2][2];
  #pragma unroll
  for (int mt=0;mt<2;mt++)
    #pragma unroll
    for (int nt=0;nt<2;nt++) acc[mt][nt] = (f32x4){0.f,0.f,0.f,0.f};
  #pragma unroll
  for (int kk = 0; kk < 128; kk += 32){
    bf16x8 af[2], bfr[2];
    #pragma unroll
    for (int mt=0;mt<2;mt++) af[mt] = *(const bf16x8*)&sA[(mt*16+l15)*136 + kk + quad*8];
    #pragma unroll
    for (int nt=0;nt<2;nt++) bfr[nt] = *(const bf16x8*)&wbfl[((w*2+nt)*16+l15)*128 + kk + quad*8];
    #pragma unroll
    for (int mt=0;mt<2;mt++)
      #pragma unroll
      for (int nt=0;nt<2;nt++)
        acc[mt][nt] = __builtin_amdgcn_mfma_f32_16x16x32_bf16(af[mt], bfr[nt], acc[mt][nt], 0, 0, 0);
  }
  #pragma unroll
  for (int mt=0;mt<2;mt++)
    #pragma unroll
    for (int nt=0;nt<2;nt++){
      int h = (w*2+nt)*16 + l15;
      #pragma unroll
      for (int reg=0;reg<4;reg++){
        int prr = rq*32 + mt*16 + quad*4 + reg;
        xfW[(b*128 + prr)*128 + h] = acc[mt][nt][reg];
      }
    }
}

// per-edge elementwise (1024 blocks x 512 thr): gelu_h, 4-way i-striping + 2-way ILP
__global__ __launch_bounds__(512) void k_edge(const float* __restrict__ xfin, float* __restrict__ xfout,
    const bf16* __restrict__ bases, const float* __restrict__ xfW,
    const float* __restrict__ bondWl, const int* __restrict__ ef,
    const int* __restrict__ length){
  int bj = blockIdx.x; int b = bj >> 7, j = bj & 127;
  int len = length[b];
  int tid = threadIdx.x; int h = tid & 127, ih = tid >> 7;   // ih in 0..3
  __shared__ float sBW[10][128];
  __shared__ int sEf[128];
  __shared__ float part[4][128];
  for (int idx = tid; idx < 1280; idx += 512) sBW[idx>>7][idx&127] = bondWl[idx];
  if (tid < 128) sEf[tid] = ef[(b*NN + tid)*NN + j];
  __syncthreads();
  float agg0 = 0.f, agg1 = 0.f;
  if (j < len){
    const float* xwb = xfW + b*NN*HH + h;
    const bf16* bb = bases + ((size_t)b*NN + j)*NN*HH + h;
    int i = ih;
    for (; i + 4 < len; i += 8){
      float v0 = gelu_h(xwb[i*128] + sBW[sEf[i]][h]);
      agg0 += v0 * b2f(bb[i*128]);
      float v1 = gelu_h(xwb[(i+4)*128] + sBW[sEf[i+4]][h]);
      agg1 += v1 * b2f(bb[(i+4)*128]);
    }
    if (i < len){
      float v0 = gelu_h(xwb[i*128] + sBW[sEf[i]][h]);
      agg0 += v0 * b2f(bb[i*128]);
    }
  }
  part[ih][h] = agg0 + agg1; __syncthreads();
  if (tid < 128){
    int o = (b*NN + j)*HH + tid;
    xfout[o] = xfin[o] + part[0][tid] + part[1][tid] + part[2][tid] + part[3][tid];
  }
}

// g1 GEMM + masked partial BN1 stats (256 blocks x 4 rows; banked atomics)
__global__ __launch_bounds__(256) void k_g1s(const float* __restrict__ xf,
    const float* __restrict__ w1t, const float* __restrict__ bias,
    const int* __restrict__ length, float* __restrict__ t1,
    float* __restrict__ gstat){
  int blk = blockIdx.x; int tid = threadIdx.x;
  int f = tid & 127, rh = tid >> 7;
  int bank = blk & 3;
  __shared__ float sx[4][128];
  __shared__ float red1[2][128], red2[2][128];
  int r0 = blk*4;
  for (int idx = tid; idx < 512; idx += 256){
    int r = idx >> 7, m = idx & 127;
    sx[r][m] = xf[(r0+r)*128 + m];
  }
  __syncthreads();
  float bsv = bias[f];
  float s=0.f, s2=0.f;
  for (int rr = rh*2; rr < rh*2+2; rr++){
    int rg = r0 + rr; int b = rg >> 7, n = rg & 127;
    float a0=bsv, a1=0.f, a2=0.f, a3=0.f;
    for (int m=0;m<128;m+=4){
      a0 += sx[rr][m]*w1t[m*128+f];
      a1 += sx[rr][m+1]*w1t[(m+1)*128+f];
      a2 += sx[rr][m+2]*w1t[(m+2)*128+f];
      a3 += sx[rr][m+3]*w1t[(m+3)*128+f];
    }
    float acc = (a0+a1)+(a2+a3);
    t1[rg*128+f] = acc;
    if (n < length[b]){ s += acc; s2 += acc*acc; }
  }
  red1[rh][f]=s; red2[rh][f]=s2; __syncthreads();
  if (tid < 128){
    atomicAdd(&gstat[bank*512 + tid], red1[0][tid]+red1[1][tid]);
    atomicAdd(&gstat[bank*512 + 128 + tid], red2[0][tid]+red2[1][tid]);
  }
}

// finalize BN1 + relu + g2 GEMM + partial BN2 stats (256 blocks x 4 rows; banked)
__global__ __launch_bounds__(256) void k_g2s(const float* __restrict__ t1,
    const float* __restrict__ g1, const float* __restrict__ bb1,
    const float* __restrict__ w2t, const float* __restrict__ bias2,
    const int* __restrict__ length, float* __restrict__ t2,
    float* __restrict__ gstat){
  int blk = blockIdx.x; int tid = threadIdx.x;
  int f = tid & 127, rh = tid >> 7;
  int bank = blk & 3;
  __shared__ float sy[4][128];
  __shared__ float red1[2][128], red2[2][128];
  int r0 = blk*4;
  float cnt = 0.f;
  for (int b=0;b<BB;b++) cnt += (float)length[b];
  float su = (gstat[f]+gstat[512+f])+(gstat[1024+f]+gstat[1536+f]);
  float sq = (gstat[128+f]+gstat[512+128+f])+(gstat[1024+128+f]+gstat[1536+128+f]);
  float mu = su/cnt;
  float var = sq/cnt - mu*mu;
  float istd = rsqrtf(fmaxf(var,0.0f)+EPSV);
  float gg = g1[f], bbv = bb1[f];
  for (int idx = tid; idx < 512; idx += 256){
    int r = idx >> 7;
    float x = t1[(r0+r)*128 + f];
    float y = (x-mu)*istd*gg + bbv;
    sy[r][f] = fmaxf(y, 0.0f);
  }
  __syncthreads();
  float bsv = bias2[f];
  float s=0.f, s2=0.f;
  for (int rr = rh*2; rr < rh*2+2; rr++){
    int rg = r0 + rr; int b = rg >> 7, n = rg & 127;
    float a0=bsv, a1=0.f, a2=0.f, a3=0.f;
    for (int m=0;m<128;m+=4){
      a0 += sy[rr][m]*w2t[m*128+f];
      a1 += sy[rr][m+1]*w2t[(m+1)*128+f];
      a2 += sy[rr][m+2]*w2t[(m+2)*128+f];
      a3 += sy[rr][m+3]*w2t[(m+3)*128+f];
    }
    float acc = (a0+a1)+(a2+a3);
    t2[rg*128+f] = acc;
    if (n < length[b]){ s += acc; s2 += acc*acc; }
  }
  red1[rh][f]=s; red2[rh][f]=s2; __syncthreads();
  if (tid < 128){
    atomicAdd(&gstat[bank*512 + 256 + tid], red1[0][tid]+red1[1][tid]);
    atomicAdd(&gstat[bank*512 + 384 + tid], red2[0][tid]+red2[1][tid]);
  }
}

// final BN2-apply fused into pooling + linear head (512 thr: 4-way node striping)
__global__ __launch_bounds__(512) void k_pool2(const float* __restrict__ xf, const float* __restrict__ t2,
                        const float* __restrict__ statp,
                        const float* __restrict__ g2, const float* __restrict__ bb2,
                        const int* __restrict__ length,
                        const float* lw, const float* lb, float* __restrict__ outp){
  int b = blockIdx.x, tid=threadIdx.x;
  int h = tid & 127, slice = tid >> 7;
  int len = length[b];
  float cnt = 0.f;
  for (int q2=0;q2<BB;q2++) cnt += (float)length[q2];
  float su = (statp[256+h]+statp[512+256+h])+(statp[1024+256+h]+statp[1536+256+h]);
  float sq = (statp[384+h]+statp[512+384+h])+(statp[1024+384+h]+statp[1536+384+h]);
  float mu = su/cnt;
  float var = sq/cnt - mu*mu;
  float istd = rsqrtf(fmaxf(var,0.0f)+EPSV);
  float gg = g2[h], bbv = bb2[h];
  float s=0.f;
  for (int n2=slice; n2<len; n2+=4){
    int o = (b*NN+n2)*HH+h;
    float x = xf[o] + fmaxf((t2[o]-mu)*istd*gg+bbv, 0.0f);
    s += x;
  }
  __shared__ float part[4][128];
  __shared__ float red[128];
  part[slice][h] = s; __syncthreads();
  if (tid < 128){
    float ss = (part[0][tid]+part[1][tid])+(part[2][tid]+part[3][tid]);
    ss /= (float)len;
    red[tid] = ss*lw[tid];
  }
  __syncthreads();
  for (int st=64;st>0;st>>=1){ if(tid<st) red[tid]+=red[tid+st]; __syncthreads(); }
  if (tid==0) outp[b]=red[0]+lb[0];
}

// ---------------- host ----------------

extern "C" void kernel_launch(void* const* d_in, const int* in_sizes, int n_in,
                              void* d_out, int out_size, void* d_ws, size_t ws_size,
                              hipStream_t stream) {
  (void)in_sizes; (void)n_in; (void)out_size; (void)ws_size;
  const float* e        = (const float*)d_in[0];
  const float* u        = (const float*)d_in[1];
  const float* atom_emb = (const float*)d_in[2];
  const float* bond_emb = (const float*)d_in[3];
  const float* eigw_W   = (const float*)d_in[4];
  const float* eigw_b   = (const float*)d_in[5];
  const float* mng      = (const float*)d_in[6];
  const float* mnb      = (const float*)d_in[7];
  const float* qkvW     = (const float*)d_in[8];
  const float* qkvb     = (const float*)d_in[9];
  const float* outW     = (const float*)d_in[10];
  const float* outb     = (const float*)d_in[11];
  const float* fng      = (const float*)d_in[12];
  const float* fnb      = (const float*)d_in[13];
  const float* ffn1W    = (const float*)d_in[14];
  const float* ffn1b    = (const float*)d_in[15];
  const float* ffn2W    = (const float*)d_in[16];
  const float* ffn2b    = (const float*)d_in[17];
  const float* decW     = (const float*)d_in[18];
  const float* decb     = (const float*)d_in[19];
  const float* fe1W     = (const float*)d_in[20];
  const float* fe1b     = (const float*)d_in[21];
  const float* fe2W     = (const float*)d_in[22];
  const float* fe2b     = (const float*)d_in[23];
  const float* preW     = (const float*)d_in[24];
  const float* preb     = (const float*)d_in[25];
  const float* f1W      = (const float*)d_in[26];
  const float* f1b      = (const float*)d_in[27];
  const float* bn1g     = (const float*)d_in[28];
  const float* bn1b     = (const float*)d_in[29];
  const float* f2W      = (const float*)d_in[30];
  const float* f2b      = (const float*)d_in[31];
  const float* bn2g     = (const float*)d_in[32];
  const float* bn2b     = (const float*)d_in[33];
  const float* linW     = (const float*)d_in[34];
  const float* linb     = (const float*)d_in[35];
  const int* nodef      = (const int*)d_in[36];
  const int* edgef      = (const int*)d_in[37];
  const int* length     = (const int*)d_in[38];

  float* outp = (float*)d_out;   // h[8] ++ new_e[4096] ++ attn[524288], f32

  char* p = (char*)d_ws;
  auto alloc = [&](size_t bytes)->void*{ void* r=(void*)p; p += (bytes+255)&~(size_t)255; return r; };
  const int TOK = BB*NN*HH;           // 131072
  float* eig   = (float*)alloc(TOK*4);
  float* q     = (float*)alloc(TOK*4);
  float* kT    = (float*)alloc(TOK*4);
  float* v     = (float*)alloc(TOK*4);
  float* attnf = (float*)alloc((size_t)BB*NHD*NN*NN*4);
  float* newe  = (float*)alloc(BB*NHD*NN*4);
  float* filt  = (float*)alloc((size_t)BB*NN*NN*4*4);
  bf16*  bases = (bf16*) alloc((size_t)BB*NN*NN*HH*2);
  float* xf0   = (float*)alloc(TOK*4);
  float* xfB   = (float*)alloc(TOK*4);
  float* xfC   = (float*)alloc(TOK*4);
  float* xfD   = (float*)alloc(TOK*4);
  float* t1    = (float*)alloc(TOK*4);
  float* t2    = (float*)alloc(TOK*4);
  float* xfW   = (float*)alloc(TOK*4);
  float* gs    = (float*)alloc(8192*4);          // 4 layers x 4 banks x 512
  ushortt* wbf = (ushortt*)alloc(81920*2);
  float* eigWT = (float*)alloc(16512*4);
  float* qkvWT = (float*)alloc(49152*4);
  float* outWT = (float*)alloc(16384*4);
  float* ffn1WT= (float*)alloc(16384*4);
  float* ffn2WT= (float*)alloc(16384*4);
  float* f1WT  = (float*)alloc(65536*4);
  float* f2WT  = (float*)alloc(65536*4);
  float* bondWall = (float*)alloc(5120*4);

  k_prep<<<512, 256, 0, stream>>>(fe2W, preW, eigw_W, qkvW, outW, ffn1W, ffn2W,
                                  f1W, f2W, atom_emb, nodef, bond_emb, preb,
                                  wbf, gs, xf0, eigWT, qkvWT, outWT, ffn1WT,
                                  ffn2WT, f1WT, f2WT, bondWall);

  // front end
  k_fe_a<<<BB*NN, 128, 0, stream>>>(e, eigWT, eigw_b, mng, mnb, qkvWT, qkvb, eig, q, kT, v);
  k_attn<<<BB*NHD*NN, 128, 0, stream>>>(q, kT, length, attnf, outp);
  k_fe_c<<<BB*NN, 128, 0, stream>>>(attnf, v, outWT, outb, fng, fnb,
                                    ffn1WT, ffn1b, ffn2WT, ffn2b, eig);
  k_dec<<<BB, 128, 0, stream>>>(eig, decW, decb, newe, outp);

  // bases
  k_filters<<<dim3(BB,8,8), dim3(16,16), 0, stream>>>(u, newe, length, filt);
  k_fe2<<<2*BB*NN, 256, 0, stream>>>(filt, fe1W, fe1b, wbf, fe2b, length, bases);

  // message passing: 4 kernels/layer
  const float* xfprev = xf0;
  float* xfcur = xfC;
  for (int l=0;l<LAY;l++){
    const ushortt* wbfl = wbf + 16384 + l*16384;
    float* gsl = gs + l*2048;
    float* gsp = gs + (l-1)*2048;
    k_xwl2<<<BB*4, 256, 0, stream>>>(xfprev, t2,
                                   (l>0)? gsp : gs,
                                   bn2g + (l>0? (l-1)*HH:0), bn2b + (l>0? (l-1)*HH:0),
                                   length, (l>0)?1:0,
                                   wbfl, xfB, xfW);
    const float* xin = (l==0)? xf0 : xfB;
    k_edge<<<BB*NN, 512, 0, stream>>>(xin, xfcur, bases, xfW, bondWall + l*1280,
                                      edgef, length);
    k_g1s<<<256, 256, 0, stream>>>(xfcur, f1WT + l*16384, f1b + l*HH, length,
                                   t1, gsl);
    k_g2s<<<256, 256, 0, stream>>>(t1, bn1g + l*HH, bn1b + l*HH,
                                   f2WT + l*16384, f2b + l*HH, length,
                                   t2, gsl);
    xfprev = xfcur;
    xfcur = (xfcur == xfC) ? xfD : xfC;
  }
  // final: BN2(layer3) applied inside pool (xfprev holds layer-3 output)
  k_pool2<<<BB, 512, 0, stream>>>(xfprev, t2, gs+3*2048,
                                  bn2g + 3*HH, bn2b + 3*HH, length, linW, linb, outp);
}

// Round 4
// 413.433 us; speedup vs baseline: 1.2249x; 1.2249x over previous
//
#include <hip/hip_runtime.h>
#include <hip/hip_bf16.h>
#include <math.h>

#define BB 8
#define NN 128
#define HH 128
#define NHD 4
#define DHD 32
#define LAY 4
#define EPSV 1e-5f

typedef __hip_bfloat16 bf16;
typedef unsigned short ushortt;
typedef short bf16x8 __attribute__((ext_vector_type(8)));
typedef float f32x4 __attribute__((ext_vector_type(4)));

__device__ __forceinline__ float b2f(bf16 x){ return __bfloat162float(x); }
__device__ __forceinline__ bf16 f2b(float x){ return __float2bfloat16(x); }
__device__ __forceinline__ float us2f(ushortt u){ return __uint_as_float(((unsigned)u)<<16); }
__device__ __forceinline__ ushortt f2us(float x){ bf16 b=__float2bfloat16(x); return *(ushortt*)&b; }
__device__ __forceinline__ float gelu_f(float x){ return 0.5f*x*(1.0f+erff(x*0.7071067811865476f)); }
// fast tanh-gelu — h-path serial loops only (k_edge); measured win there (r13)
__device__ __forceinline__ float gelu_h(float x){
  float t = 0.7978845608028654f*x*(1.0f + 0.044715f*x*x);
  float e = __expf(2.0f*t);
  float th = 1.0f - 2.0f/(e + 1.0f);
  return 0.5f*x*(1.0f + th);
}
// branch-free A&S 7.1.26 erf (|err| <= 1.5e-7) — ~16 VALU vs ocml erff's ~40+divergence.
__device__ __forceinline__ float erf_fast(float x){
  float ax = fabsf(x);
  float t = __builtin_amdgcn_rcpf(__builtin_fmaf(0.3275911f, ax, 1.0f));
  float p = __builtin_fmaf(1.061405429f, t, -1.453152027f);
  p = __builtin_fmaf(p, t, 1.421413741f);
  p = __builtin_fmaf(p, t, -0.284496736f);
  p = __builtin_fmaf(p, t, 0.254829592f);
  p = p*t;
  float e = __expf(-ax*ax);
  float y = __builtin_fmaf(-p, e, 1.0f);
  return __builtin_copysignf(y, x);
}
__device__ __forceinline__ float gelu_fe(float x){
  return 0.5f*x*(1.0f + erf_fast(x*0.7071067811865476f));
}

// ---------------- prep: bf16 weights, transposes, bondW (all layers), xf init ----------------

__global__ __launch_bounds__(256) void k_prep(const float* __restrict__ fe2W,
    const float* __restrict__ preW, const float* __restrict__ eigW,
    const float* __restrict__ qkvW, const float* __restrict__ outW,
    const float* __restrict__ ffn1W, const float* __restrict__ ffn2W,
    const float* __restrict__ f1W, const float* __restrict__ f2W,
    const float* __restrict__ aemb, const int* __restrict__ nf,
    const float* __restrict__ bemb, const float* __restrict__ preb,
    ushortt* __restrict__ wbf, float* __restrict__ gs, float* __restrict__ xf0,
    float* __restrict__ eigWT, float* __restrict__ qkvWT, float* __restrict__ outWT,
    float* __restrict__ ffn1WT, float* __restrict__ ffn2WT,
    float* __restrict__ f1WT, float* __restrict__ f2WT,
    float* __restrict__ bondWall){
  int idx = blockIdx.x*256 + threadIdx.x;    // grid covers 131072
  if (idx < 10240) gs[idx] = 0.f;            // 4 layers x 2560 (8-bank BN1 + BN2)
  if (idx < 81920){
    float v = (idx < 16384) ? fe2W[idx] : preW[idx - 16384];
    wbf[idx] = f2us(v);
  }
  if (idx < 131072){
    int node = idx >> 7, h2 = idx & 127;
    xf0[idx] = aemb[nf[node]*HH + h2];
  }
  if (idx < 16512){ int o = idx/129, kq = idx - o*129; eigWT[kq*128+o] = eigW[idx]; }
  if (idx < 49152){ int o = idx>>7, m = idx&127; qkvWT[m*384+o] = qkvW[idx]; }
  if (idx < 16384){ int o = idx>>7, m = idx&127;
    outWT[m*128+o]  = outW[idx];
    ffn1WT[m*128+o] = ffn1W[idx];
    ffn2WT[m*128+o] = ffn2W[idx];
  }
  if (idx < 65536){ int l = idx>>14, r = idx&16383; int o = r>>7, m = r&127;
    f1WT[l*16384 + m*128+o] = f1W[idx];
    f2WT[l*16384 + m*128+o] = f2W[idx];
  }
  if (idx < 5120){   // bondW for all 4 layers: bond_emb @ preW[l]^T + preb[l]
    int l = idx / 1280; int r = idx - l*1280; int e2 = r >> 7; int hcol = r & 127;
    const float* br = bemb + e2*128;
    const float* wr = preW + l*16384 + hcol*128;
    float acc = preb[l*128 + hcol];
    for (int m=0;m<128;m++) acc += br[m]*wr[m];
    bondWall[idx] = acc;
  }
}

// ---------------- front end (all f32 — precision-critical for new_e) ----------------

__global__ void k_fe_a(const float* __restrict__ e, const float* __restrict__ eigWT,
                       const float* __restrict__ eigb, const float* __restrict__ g,
                       const float* __restrict__ bt, const float* __restrict__ qkvWT,
                       const float* __restrict__ qkvb,
                       float* __restrict__ eigout, float* __restrict__ q,
                       float* __restrict__ kT, float* __restrict__ v){
  int row = blockIdx.x; int tid = threadIdx.x;
  int b = row >> 7, n = row & 127;
  __shared__ float ee[129]; __shared__ float buf[128]; __shared__ float xm[128];
  float ev = e[row];
  if (tid < 64){
    float dv = expf(-0.1439115683121279f * (float)tid);
    float pe = ev * 100.0f * dv;
    ee[1+tid] = sinf(pe);
    ee[65+tid] = cosf(pe);
  }
  if (tid == 0) ee[0] = ev;
  __syncthreads();
  float x = eigb[tid];
  for (int k2=0;k2<129;k2++) x += ee[k2]*eigWT[k2*128+tid];
  eigout[row*HH+tid] = x;
  buf[tid]=x; __syncthreads();
  for (int s2=64;s2>0;s2>>=1){ if(tid<s2) buf[tid]+=buf[tid+s2]; __syncthreads(); }
  float mean = buf[0]*(1.0f/128.0f); __syncthreads();
  float d = x-mean; buf[tid]=d*d; __syncthreads();
  for (int s2=64;s2>0;s2>>=1){ if(tid<s2) buf[tid]+=buf[tid+s2]; __syncthreads(); }
  float var = buf[0]*(1.0f/128.0f);
  xm[tid] = d*rsqrtf(var+EPSV)*g[tid]+bt[tid];
  __syncthreads();
  #pragma unroll
  for (int s3=0;s3<3;s3++){
    float acc = qkvb[s3*HH+tid];
    const float* wt = qkvWT + s3*HH + tid;
    for (int m=0;m<HH;m++) acc += xm[m]*wt[m*384];
    if (s3==0) q[row*HH+tid]=acc;
    else if (s3==1) kT[b*16384 + tid*128 + n]=acc;
    else v[row*HH+tid]=acc;
  }
}

__global__ void k_attn(const float* __restrict__ q, const float* __restrict__ kT,
                       const int* __restrict__ length,
                       float* __restrict__ attnf, float* __restrict__ outp){
  int bx = blockIdx.x;
  int qi = bx & 127, hd = (bx>>7)&3, b = bx>>9;
  int tid = threadIdx.x;
  int len = length[b];
  __shared__ float qv[DHD]; __shared__ float red[128];
  if (tid < DHD) qv[tid] = q[(b*NN+qi)*HH + hd*DHD + tid];
  __syncthreads();
  float s = -1e30f;
  if (tid < len){
    const float* kr = kT + b*16384 + hd*DHD*128 + tid;
    float sc=0.f;
    for (int d2=0; d2<DHD; d2++) sc += qv[d2]*kr[d2*128];
    s = sc * 0.17677669529663687f;
  }
  red[tid]=s; __syncthreads();
  for (int st=64;st>0;st>>=1){ if(tid<st) red[tid]=fmaxf(red[tid],red[tid+st]); __syncthreads(); }
  float mx = red[0]; __syncthreads();
  float p = (tid<len)? expf(s-mx):0.0f;
  red[tid]=p; __syncthreads();
  for (int st=64;st>0;st>>=1){ if(tid<st) red[tid]+=red[tid+st]; __syncthreads(); }
  float a = p / red[0];
  int idx = ((b*NHD+hd)*NN+qi)*NN+tid;
  attnf[idx]=a;
  outp[4104 + idx]=a;
}

__global__ void k_fe_c(const float* __restrict__ attnf, const float* __restrict__ v,
                       const float* __restrict__ outWT, const float* __restrict__ outb,
                       const float* __restrict__ fng, const float* __restrict__ fnb,
                       const float* __restrict__ w1T, const float* __restrict__ b1,
                       const float* __restrict__ w2T, const float* __restrict__ b2,
                       float* __restrict__ eig){
  int row = blockIdx.x; int b = row>>7, qi = row&127;
  int tid = threadIdx.x;
  __shared__ float c[128]; __shared__ float buf[128]; __shared__ float xm[128]; __shared__ float tt[128];
  int hd = tid>>5;
  const float* ar = attnf + ((b*NHD+hd)*NN+qi)*NN;
  float acc=0.f;
  for (int j=0;j<NN;j++) acc += ar[j]*v[(b*NN+j)*HH+tid];
  c[tid]=acc; __syncthreads();
  float o = outb[tid];
  for (int m=0;m<HH;m++) o += c[m]*outWT[m*128+tid];
  float x = eig[row*HH+tid] + o;
  buf[tid]=x; __syncthreads();
  for (int s2=64;s2>0;s2>>=1){ if(tid<s2) buf[tid]+=buf[tid+s2]; __syncthreads(); }
  float mean=buf[0]*(1.f/128.f); __syncthreads();
  float d=x-mean; buf[tid]=d*d; __syncthreads();
  for (int s2=64;s2>0;s2>>=1){ if(tid<s2) buf[tid]+=buf[tid+s2]; __syncthreads(); }
  float var=buf[0]*(1.f/128.f);
  xm[tid]=d*rsqrtf(var+EPSV)*fng[tid]+fnb[tid];
  __syncthreads();
  float a1=b1[tid];
  for (int m=0;m<HH;m++) a1+=xm[m]*w1T[m*128+tid];
  tt[tid]=gelu_f(a1); __syncthreads();
  float a2=b2[tid];
  for (int m=0;m<HH;m++) a2+=tt[m]*w2T[m*128+tid];
  eig[row*HH+tid]=x+a2;
}

__global__ void k_dec(const float* __restrict__ eig, const float* dW, const float* db,
                      float* __restrict__ newe, float* __restrict__ outp){
  int b = blockIdx.x, n = threadIdx.x;
  __shared__ float w[NHD*HH];
  for (int i=n;i<NHD*HH;i+=128) w[i]=dW[i];
  __syncthreads();
  float acc[NHD];
  #pragma unroll
  for (int kk=0;kk<NHD;kk++) acc[kk]=db[kk];
  const float* er = eig + (b*NN+n)*HH;
  for (int h2=0;h2<HH;h2++){
    float ev = er[h2];
    #pragma unroll
    for (int kk=0;kk<NHD;kk++) acc[kk]+=ev*w[kk*HH+h2];
  }
  #pragma unroll
  for (int kk=0;kk<NHD;kk++){
    int idx=(b*NHD+kk)*NN+n; newe[idx]=acc[kk];
    outp[8 + idx]=acc[kk];
  }
}

// ---------------- bases ----------------

// filt[b][n][p][k] only consumed for n<len, p<len (via k_fe2 -> k_edge) — skip dead tiles
__global__ void k_filters(const float* __restrict__ u, const float* __restrict__ newe,
                          const int* __restrict__ length, float* __restrict__ filt){
  int b = blockIdx.x, n0 = blockIdx.y*16, p0 = blockIdx.z*16;
  int len = length[b];
  if (n0 >= len || p0 >= len) return;   // block-uniform: output never read
  int tx = threadIdx.x, ty = threadIdx.y; int tid = ty*16+tx;
  __shared__ float un[16][17], upt[16][17], wk[4][16];
  float acc[4]={0.f,0.f,0.f,0.f};
  for (int mt=0; mt<8; mt++){
    __syncthreads();
    un[ty][tx]  = u[(b*NN+n0+ty)*NN + mt*16+tx];
    upt[tx][ty] = u[(b*NN+p0+ty)*NN + mt*16+tx];
    if (tid<64) wk[tid>>4][tid&15] = newe[(b*NHD+(tid>>4))*NN + mt*16 + (tid&15)];
    __syncthreads();
    #pragma unroll
    for (int mm=0;mm<16;mm++){
      float pr = un[ty][mm]*upt[mm][tx];
      #pragma unroll
      for (int kk=0;kk<4;kk++) acc[kk] += pr*wk[kk][mm];
    }
  }
  float4 o; o.x=acc[0];o.y=acc[1];o.z=acc[2];o.w=acc[3];
  *(float4*)&filt[((b*NN+n0+ty)*NN+p0+tx)*4] = o;
}

// bases: LDS-staged fe2 weights; fast erf; length-masked
__global__ __launch_bounds__(256) void k_fe2(const float* __restrict__ filt,
    const float* __restrict__ w1g, const float* __restrict__ b1g,
    const ushortt* __restrict__ w2bf, const float* __restrict__ b2g,
    const int* __restrict__ length,
    bf16* __restrict__ bases){
  int blk = blockIdx.x;
  int bi = blk >> 1;            // b*128 + n
  int r0 = (blk & 1)*64;
  int b = bi >> 7;
  int nloc = bi & 127;
  int len = length[b];
  if (nloc >= len || r0 >= len) return;   // block-uniform: whole output slab unused
  int tid = threadIdx.x;
  int lane = tid & 63, w = tid >> 6, quad = lane >> 4, l15 = lane & 15;
  // hoist the long-latency filt load above staging so HBM latency hides under the copy
  int pr = r0 + w*16 + l15;                 // A row (m index) this lane feeds
  float4 f4 = ((const float4*)filt)[bi*128 + pr];
  __shared__ alignas(16) ushortt sW2[128*136];   // 34816 B; reused as sT[64][132] later
  __shared__ float w1p[128*8];                    // rows: {b1, w0..w4, pad, pad}
  __shared__ float b2s[128];
  for (int idx = tid; idx < 2048; idx += 256){    // 32KB weight copy, 16B chunks
    int r = idx >> 4, cb = idx & 15;
    *(uint4*)&sW2[r*136 + cb*8] = *(const uint4*)&w2bf[r*128 + cb*8];
  }
  for (int idx = tid; idx < 1024; idx += 256){
    int r = idx >> 3, c = idx & 7;
    w1p[idx] = (c==0) ? b1g[r] : (c<=5 ? w1g[r*5 + c-1] : 0.f);
  }
  if (tid < 128) b2s[tid] = b2g[tid];
  __syncthreads();
  // wave w owns rows [r0+16w, r0+16w+16); rows >= len may see uninit filt — garbage
  // stays confined to that MFMA output row (A-row == C-row) and is never stored.
  bool wact = (r0 + w*16) < len;
  f32x4 acc[8];
  #pragma unroll
  for (int nt=0;nt<8;nt++) acc[nt] = (f32x4){0.f,0.f,0.f,0.f};
  if (wact){
    float dg = (pr == nloc) ? 1.0f : 0.0f;
    for (int kk = 0; kk < 128; kk += 32){
      bf16x8 af;
      #pragma unroll
      for (int j=0;j<8;j++){
        int m = kk + quad*8 + j;
        const float4 wa = *(const float4*)&w1p[m*8];     // b1, w0, w1, w2
        const float2 wb = *(const float2*)&w1p[m*8+4];   // w3, w4
        float a = wa.x + wa.y*dg + wa.z*f4.x + wa.w*f4.y + wb.x*f4.z + wb.y*f4.w;
        af[j] = (short)f2us(gelu_fe(a));
      }
      #pragma unroll
      for (int nt=0;nt<8;nt++){
        bf16x8 bfr = *(const bf16x8*)&sW2[(nt*16+l15)*136 + kk + quad*8];
        acc[nt] = __builtin_amdgcn_mfma_f32_16x16x32_bf16(af, bfr, acc[nt], 0, 0, 0);
      }
    }
  }
  __syncthreads();              // all sW2 reads complete -> safe to reuse as sT
  ushortt* sT = sW2;
  if (wact){
    #pragma unroll
    for (int nt=0;nt<8;nt++){
      int h = nt*16 + l15;
      float bb = b2s[h];
      #pragma unroll
      for (int reg=0;reg<4;reg++){
        int lr = w*16 + quad*4 + reg;
        sT[lr*132 + h] = f2us(gelu_fe(acc[nt][reg] + bb));
      }
    }
  }
  __syncthreads();
  int rmax = len - r0; if (rmax > 64) rmax = 64;   // only rows i<len are ever read
  ushort4* gout = (ushort4*)(bases + (size_t)bi*16384 + r0*128);
  for (int idx = tid; idx < rmax*32; idx += 256){
    int row = idx >> 5, seg = idx & 31;
    gout[idx] = *(const ushort4*)&sT[row*132 + seg*4];
  }
}

// ---------------- message passing ----------------
// gs layout per layer (stride 2560 floats):
//   [bank 0..7][ sum1(128) | sq1(128) ]  (8-way banked BN1 partials from k_edge)
//   + 2048: [ sum2(128) | sq2(128) ]     (BN2 partials from k_g2s, unbanked as before)

// per-layer (32 blocks): fused BN2-apply of previous layer; xfW = xfB @ preW^T (MFMA)
__global__ __launch_bounds__(256) void k_xwl2(const float* __restrict__ xfprev,
    const float* __restrict__ t2, const float* __restrict__ gsum2p,
    const float* __restrict__ gsq2p, const float* __restrict__ g2p,
    const float* __restrict__ bb2p, const int* __restrict__ length, int prevapply,
    const ushortt* __restrict__ wbfl, float* __restrict__ xfB,
    float* __restrict__ xfW){
  int blk = blockIdx.x;
  int b = blk >> 2, rq = blk & 3;
  int tid = threadIdx.x;
  int lane = tid & 63, w = tid >> 6, quad = lane >> 4, l15 = lane & 15;
  __shared__ alignas(16) ushortt sA[32*136];
  __shared__ float smu[128], sistd[128], sg[128], sbb[128];
  if (prevapply && tid < 128){
    float cnt = 0.f;
    for (int q2=0;q2<BB;q2++) cnt += (float)length[q2];
    float mu = gsum2p[tid]/cnt;
    float var = gsq2p[tid]/cnt - mu*mu;
    smu[tid]=mu; sistd[tid]=rsqrtf(fmaxf(var,0.0f)+EPSV);
    sg[tid]=g2p[tid]; sbb[tid]=bb2p[tid];
  }
  __syncthreads();
  for (int idx = tid; idx < 1024; idx += 256){
    int r = idx >> 5, c = idx & 31;
    int gr = b*128 + rq*32 + r;
    float4 xv = ((const float4*)xfprev)[gr*32 + c];
    if (prevapply){
      float4 tv = ((const float4*)t2)[gr*32 + c];
      int f0 = c*4;
      xv.x += fmaxf((tv.x-smu[f0+0])*sistd[f0+0]*sg[f0+0]+sbb[f0+0], 0.f);
      xv.y += fmaxf((tv.y-smu[f0+1])*sistd[f0+1]*sg[f0+1]+sbb[f0+1], 0.f);
      xv.z += fmaxf((tv.z-smu[f0+2])*sistd[f0+2]*sg[f0+2]+sbb[f0+2], 0.f);
      xv.w += fmaxf((tv.w-smu[f0+3])*sistd[f0+3]*sg[f0+3]+sbb[f0+3], 0.f);
      ((float4*)xfB)[gr*32 + c] = xv;
    }
    ushort4 o;
    o.x=f2us(xv.x); o.y=f2us(xv.y); o.z=f2us(xv.z); o.w=f2us(xv.w);
    *(ushort4*)&sA[r*136 + c*4] = o;
  }
  __syncthreads();
  f32x4 acc[2][2];
  #pragma unroll
  for (int mt=0;mt<2;mt++)
    #pragma unroll
    for (int nt=0;nt<2;nt++) acc[mt][nt] = (f32x4){0.f,0.f,0.f,0.f};
  #pragma unroll
  for (int kk = 0; kk < 128; kk += 32){
    bf16x8 af[2], bfr[2];
    #pragma unroll
    for (int mt=0;mt<2;mt++) af[mt] = *(const bf16x8*)&sA[(mt*16+l15)*136 + kk + quad*8];
    #pragma unroll
    for (int nt=0;nt<2;nt++) bfr[nt] = *(const bf16x8*)&wbfl[((w*2+nt)*16+l15)*128 + kk + quad*8];
    #pragma unroll
    for (int mt=0;mt<2;mt++)
      #pragma unroll
      for (int nt=0;nt<2;nt++)
        acc[mt][nt] = __builtin_amdgcn_mfma_f32_16x16x32_bf16(af[mt], bfr[nt], acc[mt][nt], 0, 0, 0);
  }
  #pragma unroll
  for (int mt=0;mt<2;mt++)
    #pragma unroll
    for (int nt=0;nt<2;nt++){
      int h = (w*2+nt)*16 + l15;
      #pragma unroll
      for (int reg=0;reg<4;reg++){
        int prr = rq*32 + mt*16 + quad*4 + reg;
        xfW[(b*128 + prr)*128 + h] = acc[mt][nt][reg];
      }
    }
}

// per-edge elementwise + FUSED g1 GEMM + BN1 partial stats.
// Block (b,j) produces the whole xf row j, which is exactly what the g1 row-GEMM
// needs -> fuse: saves 4 dispatches + 4x xf global round-trip + LDS restaging.
__global__ __launch_bounds__(512) void k_edge(const float* __restrict__ xfin, float* __restrict__ xfout,
    const bf16* __restrict__ bases, const float* __restrict__ xfW,
    const float* __restrict__ bondWl, const int* __restrict__ ef,
    const int* __restrict__ length,
    const float* __restrict__ w1t, const float* __restrict__ bias1,
    float* __restrict__ t1, float* __restrict__ gst){
  int bj = blockIdx.x; int b = bj >> 7, j = bj & 127;
  int len = length[b];
  int tid = threadIdx.x; int h = tid & 127, ih = tid >> 7;   // ih in 0..3
  __shared__ float sBW[10][128];
  __shared__ int sEf[128];
  __shared__ float part[4][128];
  for (int idx = tid; idx < 1280; idx += 512) sBW[idx>>7][idx&127] = bondWl[idx];
  if (tid < 128) sEf[tid] = ef[(b*NN + tid)*NN + j];
  __syncthreads();
  float agg = 0.f;
  if (j < len){
    const float* xwb = xfW + b*NN*HH + h;
    const bf16* bb = bases + ((size_t)b*NN + j)*NN*HH + h;
    for (int i = ih; i < len; i += 4){
      float vv = gelu_h(xwb[i*128] + sBW[sEf[i]][h]);
      agg += vv * b2f(bb[i*128]);
    }
  }
  part[ih][h] = agg; __syncthreads();
  if (tid < 128){
    int o = (b*NN + j)*HH + tid;
    float xrow = xfin[o] + part[0][tid] + part[1][tid] + part[2][tid] + part[3][tid];
    xfout[o] = xrow;
    part[0][tid] = xrow;        // each tid<128 reads its own part[*][tid] before this
  }
  __syncthreads();
  // g1 GEMM on the row: feature f = h; slice ih covers m in [ih*32, ih*32+32)
  float acc = (ih==0) ? bias1[h] : 0.f;
  {
    const float* wcol = w1t + h;
    int m0 = ih*32;
    for (int m = m0; m < m0+32; m++) acc += part[0][m]*wcol[m*128];
  }
  float* red = &sBW[0][0];      // sBW no longer needed; reuse as red[4][128]
  __syncthreads();              // part[0][m] reads done before red overwrites? (different buffers; this sync orders red reuse vs sBW reads above)
  red[ih*128 + h] = acc; __syncthreads();
  if (tid < 128){
    float t1v = red[tid] + red[128+tid] + red[256+tid] + red[384+tid];
    t1[(b*NN + j)*HH + tid] = t1v;
    if (j < len){
      int bank = bj & 7;
      atomicAdd(&gst[bank*256 + tid], t1v);
      atomicAdd(&gst[bank*256 + 128 + tid], t1v*t1v);
    }
  }
}

// finalize BN1 (sum 8 banks) + relu + g2 GEMM + partial BN2 stats (256 blocks x 4 rows)
__global__ __launch_bounds__(256) void k_g2s(const float* __restrict__ t1,
    const float* __restrict__ gstL,
    const float* __restrict__ g1, const float* __restrict__ bb1,
    const float* __restrict__ w2t, const float* __restrict__ bias2,
    const int* __restrict__ length, float* __restrict__ t2){
  int blk = blockIdx.x; int tid = threadIdx.x;
  int f = tid & 127, rh = tid >> 7;
  __shared__ float sy[4][128];
  __shared__ float red1[2][128], red2[2][128];
  int r0 = blk*4;
  float cnt = 0.f;
  for (int b=0;b<BB;b++) cnt += (float)length[b];
  float su = 0.f, sq = 0.f;
  #pragma unroll
  for (int k=0;k<8;k++){ su += gstL[k*256 + f]; sq += gstL[k*256 + 128 + f]; }
  float mu = su/cnt;
  float var = sq/cnt - mu*mu;
  float istd = rsqrtf(fmaxf(var,0.0f)+EPSV);
  float gg = g1[f], bbv = bb1[f];
  for (int idx = tid; idx < 512; idx += 256){
    int r = idx >> 7;
    float x = t1[(r0+r)*128 + f];
    float y = (x-mu)*istd*gg + bbv;
    sy[r][f] = fmaxf(y, 0.0f);
  }
  __syncthreads();
  float bsv = bias2[f];
  float s=0.f, s2=0.f;
  for (int rr = rh*2; rr < rh*2+2; rr++){
    int rg = r0 + rr; int b = rg >> 7, n = rg & 127;
    float acc = bsv;
    for (int m=0;m<128;m++) acc += sy[rr][m]*w2t[m*128+f];
    t2[rg*128+f] = acc;
    if (n < length[b]){ s += acc; s2 += acc*acc; }
  }
  red1[rh][f]=s; red2[rh][f]=s2; __syncthreads();
  if (tid < 128){
    atomicAdd((float*)&gstL[2048 + tid], red1[0][tid]+red1[1][tid]);
    atomicAdd((float*)&gstL[2048 + 128 + tid], red2[0][tid]+red2[1][tid]);
  }
}

// final BN2-apply fused into pooling + linear head
__global__ void k_pool2(const float* __restrict__ xf, const float* __restrict__ t2,
                        const float* __restrict__ gsum2, const float* __restrict__ gsq2,
                        const float* __restrict__ g2, const float* __restrict__ bb2,
                        const int* __restrict__ length,
                        const float* lw, const float* lb, float* __restrict__ outp){
  int b = blockIdx.x, tid=threadIdx.x;
  int len = length[b];
  float cnt = 0.f;
  for (int q2=0;q2<BB;q2++) cnt += (float)length[q2];
  float mu = gsum2[tid]/cnt;
  float var = gsq2[tid]/cnt - mu*mu;
  float istd = rsqrtf(fmaxf(var,0.0f)+EPSV);
  float gg = g2[tid], bbv = bb2[tid];
  float s=0.f;
  for (int n2=0;n2<len;n2++){
    int o = (b*NN+n2)*HH+tid;
    float x = xf[o] + fmaxf((t2[o]-mu)*istd*gg+bbv, 0.0f);
    s += x;
  }
  s /= (float)len;
  __shared__ float red[128];
  red[tid]=s*lw[tid]; __syncthreads();
  for (int st=64;st>0;st>>=1){ if(tid<st) red[tid]+=red[tid+st]; __syncthreads(); }
  if (tid==0) outp[b]=red[0]+lb[0];
}

// ---------------- host ----------------

extern "C" void kernel_launch(void* const* d_in, const int* in_sizes, int n_in,
                              void* d_out, int out_size, void* d_ws, size_t ws_size,
                              hipStream_t stream) {
  (void)in_sizes; (void)n_in; (void)out_size; (void)ws_size;
  const float* e        = (const float*)d_in[0];
  const float* u        = (const float*)d_in[1];
  const float* atom_emb = (const float*)d_in[2];
  const float* bond_emb = (const float*)d_in[3];
  const float* eigw_W   = (const float*)d_in[4];
  const float* eigw_b   = (const float*)d_in[5];
  const float* mng      = (const float*)d_in[6];
  const float* mnb      = (const float*)d_in[7];
  const float* qkvW     = (const float*)d_in[8];
  const float* qkvb     = (const float*)d_in[9];
  const float* outW     = (const float*)d_in[10];
  const float* outb     = (const float*)d_in[11];
  const float* fng      = (const float*)d_in[12];
  const float* fnb      = (const float*)d_in[13];
  const float* ffn1W    = (const float*)d_in[14];
  const float* ffn1b    = (const float*)d_in[15];
  const float* ffn2W    = (const float*)d_in[16];
  const float* ffn2b    = (const float*)d_in[17];
  const float* decW     = (const float*)d_in[18];
  const float* decb     = (const float*)d_in[19];
  const float* fe1W     = (const float*)d_in[20];
  const float* fe1b     = (const float*)d_in[21];
  const float* fe2W     = (const float*)d_in[22];
  const float* fe2b     = (const float*)d_in[23];
  const float* preW     = (const float*)d_in[24];
  const float* preb     = (const float*)d_in[25];
  const float* f1W      = (const float*)d_in[26];
  const float* f1b      = (const float*)d_in[27];
  const float* bn1g     = (const float*)d_in[28];
  const float* bn1b     = (const float*)d_in[29];
  const float* f2W      = (const float*)d_in[30];
  const float* f2b      = (const float*)d_in[31];
  const float* bn2g     = (const float*)d_in[32];
  const float* bn2b     = (const float*)d_in[33];
  const float* linW     = (const float*)d_in[34];
  const float* linb     = (const float*)d_in[35];
  const int* nodef      = (const int*)d_in[36];
  const int* edgef      = (const int*)d_in[37];
  const int* length     = (const int*)d_in[38];

  float* outp = (float*)d_out;   // h[8] ++ new_e[4096] ++ attn[524288], f32

  char* p = (char*)d_ws;
  auto alloc = [&](size_t bytes)->void*{ void* r=(void*)p; p += (bytes+255)&~(size_t)255; return r; };
  const int TOK = BB*NN*HH;           // 131072
  float* eig   = (float*)alloc(TOK*4);
  float* q     = (float*)alloc(TOK*4);
  float* kT    = (float*)alloc(TOK*4);
  float* v     = (float*)alloc(TOK*4);
  float* attnf = (float*)alloc((size_t)BB*NHD*NN*NN*4);
  float* newe  = (float*)alloc(BB*NHD*NN*4);
  float* filt  = (float*)alloc((size_t)BB*NN*NN*4*4);
  bf16*  bases = (bf16*) alloc((size_t)BB*NN*NN*HH*2);
  float* xf0   = (float*)alloc(TOK*4);
  float* xfB   = (float*)alloc(TOK*4);
  float* xfC   = (float*)alloc(TOK*4);
  float* xfD   = (float*)alloc(TOK*4);
  float* t1    = (float*)alloc(TOK*4);
  float* t2    = (float*)alloc(TOK*4);
  float* xfW   = (float*)alloc(TOK*4);
  float* gs    = (float*)alloc(10240*4);         // 4 layers x 2560
  ushortt* wbf = (ushortt*)alloc(81920*2);
  float* eigWT = (float*)alloc(16512*4);
  float* qkvWT = (float*)alloc(49152*4);
  float* outWT = (float*)alloc(16384*4);
  float* ffn1WT= (float*)alloc(16384*4);
  float* ffn2WT= (float*)alloc(16384*4);
  float* f1WT  = (float*)alloc(65536*4);
  float* f2WT  = (float*)alloc(65536*4);
  float* bondWall = (float*)alloc(5120*4);

  k_prep<<<512, 256, 0, stream>>>(fe2W, preW, eigw_W, qkvW, outW, ffn1W, ffn2W,
                                  f1W, f2W, atom_emb, nodef, bond_emb, preb,
                                  wbf, gs, xf0, eigWT, qkvWT, outWT, ffn1WT,
                                  ffn2WT, f1WT, f2WT, bondWall);

  // front end
  k_fe_a<<<BB*NN, 128, 0, stream>>>(e, eigWT, eigw_b, mng, mnb, qkvWT, qkvb, eig, q, kT, v);
  k_attn<<<BB*NHD*NN, 128, 0, stream>>>(q, kT, length, attnf, outp);
  k_fe_c<<<BB*NN, 128, 0, stream>>>(attnf, v, outWT, outb, fng, fnb,
                                    ffn1WT, ffn1b, ffn2WT, ffn2b, eig);
  k_dec<<<BB, 128, 0, stream>>>(eig, decW, decb, newe, outp);

  // bases
  k_filters<<<dim3(BB,8,8), dim3(16,16), 0, stream>>>(u, newe, length, filt);
  k_fe2<<<2*BB*NN, 256, 0, stream>>>(filt, fe1W, fe1b, wbf, fe2b, length, bases);

  // message passing: 3 kernels/layer (edge+g1 fused)
  const float* xfprev = xf0;
  float* xfcur = xfC;
  for (int l=0;l<LAY;l++){
    const ushortt* wbfl = wbf + 16384 + l*16384;
    float* gsl = gs + l*2560;
    float* gsp = gs + (l-1)*2560;
    k_xwl2<<<BB*4, 256, 0, stream>>>(xfprev, t2,
                                   (l>0)? gsp+2048 : gs, (l>0)? gsp+2048+128 : gs,
                                   bn2g + (l>0? (l-1)*HH:0), bn2b + (l>0? (l-1)*HH:0),
                                   length, (l>0)?1:0,
                                   wbfl, xfB, xfW);
    const float* xin = (l==0)? xf0 : xfB;
    k_edge<<<BB*NN, 512, 0, stream>>>(xin, xfcur, bases, xfW, bondWall + l*1280,
                                      edgef, length,
                                      f1WT + l*16384, f1b + l*HH, t1, gsl);
    k_g2s<<<256, 256, 0, stream>>>(t1, gsl, bn1g + l*HH, bn1b + l*HH,
                                   f2WT + l*16384, f2b + l*HH, length, t2);
    xfprev = xfcur;
    xfcur = (xfcur == xfC) ? xfD : xfC;
  }
  // final: BN2(layer3) applied inside pool (xfprev holds layer-3 output)
  k_pool2<<<BB, 128, 0, stream>>>(xfprev, t2, gs+3*2560+2048, gs+3*2560+2048+128,
                                  bn2g + 3*HH, bn2b + 3*HH, length, linW, linb, outp);
}

// Round 6
// 409.877 us; speedup vs baseline: 1.2355x; 1.0087x over previous
//
#include <hip/hip_runtime.h>
#include <hip/hip_bf16.h>
#include <math.h>

#define BB 8
#define NN 128
#define HH 128
#define NHD 4
#define DHD 32
#define LAY 4
#define EPSV 1e-5f

typedef __hip_bfloat16 bf16;
typedef unsigned short ushortt;
typedef short bf16x8 __attribute__((ext_vector_type(8)));
typedef float f32x4 __attribute__((ext_vector_type(4)));

__device__ __forceinline__ float b2f(bf16 x){ return __bfloat162float(x); }
__device__ __forceinline__ bf16 f2b(float x){ return __float2bfloat16(x); }
__device__ __forceinline__ ushortt f2us(float x){ bf16 b=__float2bfloat16(x); return *(ushortt*)&b; }
__device__ __forceinline__ float gelu_f(float x){ return 0.5f*x*(1.0f+erff(x*0.7071067811865476f)); }
// fast tanh-gelu — h-path serial loops only (k_edge); measured win there
__device__ __forceinline__ float gelu_h(float x){
  float t = 0.7978845608028654f*x*(1.0f + 0.044715f*x*x);
  float e = __expf(2.0f*t);
  float th = 1.0f - 2.0f/(e + 1.0f);
  return 0.5f*x*(1.0f + th);
}
// branch-free A&S 7.1.26 erf (|err| <= 1.5e-7)
__device__ __forceinline__ float erf_fast(float x){
  float ax = fabsf(x);
  float t = __builtin_amdgcn_rcpf(__builtin_fmaf(0.3275911f, ax, 1.0f));
  float p = __builtin_fmaf(1.061405429f, t, -1.453152027f);
  p = __builtin_fmaf(p, t, 1.421413741f);
  p = __builtin_fmaf(p, t, -0.284496736f);
  p = __builtin_fmaf(p, t, 0.254829592f);
  p = p*t;
  float e = __expf(-ax*ax);
  float y = __builtin_fmaf(-p, e, 1.0f);
  return __builtin_copysignf(y, x);
}
__device__ __forceinline__ float gelu_fe(float x){
  return 0.5f*x*(1.0f + erf_fast(x*0.7071067811865476f));
}

// ---------------- prep ----------------

__global__ __launch_bounds__(256) void k_prep(const float* __restrict__ fe2W,
    const float* __restrict__ preW, const float* __restrict__ eigW,
    const float* __restrict__ qkvW, const float* __restrict__ outW,
    const float* __restrict__ ffn1W, const float* __restrict__ ffn2W,
    const float* __restrict__ f1W, const float* __restrict__ f2W,
    const float* __restrict__ aemb, const int* __restrict__ nf,
    const float* __restrict__ bemb, const float* __restrict__ preb,
    ushortt* __restrict__ wbf, float* __restrict__ gs, float* __restrict__ xf0,
    float* __restrict__ eigWT, float* __restrict__ qkvWT, float* __restrict__ outWT,
    float* __restrict__ ffn1WT, float* __restrict__ ffn2WT,
    float* __restrict__ f1WT, float* __restrict__ f2WT,
    float* __restrict__ bondWall){
  int idx = blockIdx.x*256 + threadIdx.x;    // grid covers 131072
  if (idx < 10240) gs[idx] = 0.f;            // 4 layers x 2560
  if (idx < 81920){
    float v = (idx < 16384) ? fe2W[idx] : preW[idx - 16384];
    wbf[idx] = f2us(v);
  }
  if (idx < 131072){
    int node = idx >> 7, h2 = idx & 127;
    xf0[idx] = aemb[nf[node]*HH + h2];
  }
  if (idx < 16512){ int o = idx/129, kq = idx - o*129; eigWT[kq*128+o] = eigW[idx]; }
  if (idx < 49152){ int o = idx>>7, m = idx&127; qkvWT[m*384+o] = qkvW[idx]; }
  if (idx < 16384){ int o = idx>>7, m = idx&127;
    outWT[m*128+o]  = outW[idx];
    ffn1WT[m*128+o] = ffn1W[idx];
    ffn2WT[m*128+o] = ffn2W[idx];
  }
  if (idx < 65536){ int l = idx>>14, r = idx&16383; int o = r>>7, m = r&127;
    f1WT[l*16384 + m*128+o] = f1W[idx];
    f2WT[l*16384 + m*128+o] = f2W[idx];
  }
  if (idx < 5120){
    int l = idx / 1280; int r = idx - l*1280; int e2 = r >> 7; int hcol = r & 127;
    const float* br = bemb + e2*128;
    const float* wr = preW + l*16384 + hcol*128;
    float acc = preb[l*128 + hcol];
    for (int m=0;m<128;m++) acc += br[m]*wr[m];
    bondWall[idx] = acc;
  }
}

// ---------------- front end ----------------

__global__ void k_fe_a(const float* __restrict__ e, const float* __restrict__ eigWT,
                       const float* __restrict__ eigb, const float* __restrict__ g,
                       const float* __restrict__ bt, const float* __restrict__ qkvWT,
                       const float* __restrict__ qkvb,
                       float* __restrict__ eigout, float* __restrict__ q,
                       float* __restrict__ kT, float* __restrict__ v){
  int row = blockIdx.x; int tid = threadIdx.x;
  int b = row >> 7, n = row & 127;
  __shared__ float ee[129]; __shared__ float buf[128]; __shared__ float xm[128];
  float ev = e[row];
  if (tid < 64){
    float dv = expf(-0.1439115683121279f * (float)tid);
    float pe = ev * 100.0f * dv;
    ee[1+tid] = sinf(pe);
    ee[65+tid] = cosf(pe);
  }
  if (tid == 0) ee[0] = ev;
  __syncthreads();
  float x = eigb[tid];
  for (int k2=0;k2<129;k2++) x += ee[k2]*eigWT[k2*128+tid];
  eigout[row*HH+tid] = x;
  buf[tid]=x; __syncthreads();
  for (int s2=64;s2>0;s2>>=1){ if(tid<s2) buf[tid]+=buf[tid+s2]; __syncthreads(); }
  float mean = buf[0]*(1.0f/128.0f); __syncthreads();
  float d = x-mean; buf[tid]=d*d; __syncthreads();
  for (int s2=64;s2>0;s2>>=1){ if(tid<s2) buf[tid]+=buf[tid+s2]; __syncthreads(); }
  float var = buf[0]*(1.0f/128.0f);
  xm[tid] = d*rsqrtf(var+EPSV)*g[tid]+bt[tid];
  __syncthreads();
  #pragma unroll
  for (int s3=0;s3<3;s3++){
    float acc = qkvb[s3*HH+tid];
    const float* wt = qkvWT + s3*HH + tid;
    for (int m=0;m<HH;m++) acc += xm[m]*wt[m*384];
    if (s3==0) q[row*HH+tid]=acc;
    else if (s3==1) kT[b*16384 + tid*128 + n]=acc;
    else v[row*HH+tid]=acc;
  }
}

// fused attention + out-proj + LN + FFN + dec per (b,qi): block-local, exact
// per-item arithmetic of the R4 k_attn/k_fe_c/k_dec kernels.
__global__ __launch_bounds__(512) void k_attc(const float* __restrict__ q,
    const float* __restrict__ kT, const float* __restrict__ v,
    const float* __restrict__ eig, const int* __restrict__ length,
    const float* __restrict__ outWT, const float* __restrict__ outb,
    const float* __restrict__ fng, const float* __restrict__ fnb,
    const float* __restrict__ w1T, const float* __restrict__ b1,
    const float* __restrict__ w2T, const float* __restrict__ b2,
    const float* __restrict__ dW, const float* __restrict__ db,
    float* __restrict__ newe, float* __restrict__ outp){
  int row = blockIdx.x; int b = row>>7, qi = row&127;
  int tid = threadIdx.x;
  int hg = tid>>7, lt = tid&127;
  int len = length[b];
  __shared__ float qv[4][DHD];
  __shared__ float red[4][128];
  __shared__ float satt[4][128];
  __shared__ float sc[128], sbuf[128], sxm[128], stt[128], sx[128];
  // ---- attention (4 heads in lockstep; exact k_attn arithmetic) ----
  if (lt < DHD) qv[hg][lt] = q[(b*NN+qi)*HH + hg*DHD + lt];
  __syncthreads();
  float s = -1e30f;
  if (lt < len){
    const float* kr = kT + b*16384 + hg*DHD*128 + lt;
    float scr=0.f;
    for (int d2=0; d2<DHD; d2++) scr += qv[hg][d2]*kr[d2*128];
    s = scr * 0.17677669529663687f;
  }
  red[hg][lt]=s; __syncthreads();
  for (int st=64;st>0;st>>=1){ if(lt<st) red[hg][lt]=fmaxf(red[hg][lt],red[hg][lt+st]); __syncthreads(); }
  float mx = red[hg][0]; __syncthreads();
  float pp = (lt<len)? expf(s-mx):0.0f;
  red[hg][lt]=pp; __syncthreads();
  for (int st=64;st>0;st>>=1){ if(lt<st) red[hg][lt]+=red[hg][lt+st]; __syncthreads(); }
  float a = pp / red[hg][0];
  satt[hg][lt] = a;
  outp[4104 + ((b*NHD+hg)*NN+qi)*NN + lt] = a;
  __syncthreads();
  // ---- ctx + out-proj + LN (exact k_fe_c arithmetic, tid<128) ----
  if (tid < 128){
    int hd = tid>>5;
    float acc=0.f;
    for (int j=0;j<NN;j++) acc += satt[hd][j]*v[(b*NN+j)*HH+tid];
    sc[tid]=acc;
  }
  __syncthreads();
  if (tid < 128){
    float o = outb[tid];
    for (int m=0;m<HH;m++) o += sc[m]*outWT[m*128+tid];
    float x = eig[row*HH+tid] + o;
    sx[tid] = x; sbuf[tid] = x;
  }
  __syncthreads();
  for (int s2=64;s2>0;s2>>=1){ if(tid<s2) sbuf[tid]+=sbuf[tid+s2]; __syncthreads(); }
  float mean = sbuf[0]*(1.f/128.f); __syncthreads();
  if (tid < 128){ float d = sx[tid]-mean; sbuf[tid]=d*d; }
  __syncthreads();
  for (int s2=64;s2>0;s2>>=1){ if(tid<s2) sbuf[tid]+=sbuf[tid+s2]; __syncthreads(); }
  float var = sbuf[0]*(1.f/128.f);
  if (tid < 128){
    float d = sx[tid]-mean;
    sxm[tid] = d*rsqrtf(var+EPSV)*fng[tid]+fnb[tid];
  }
  __syncthreads();
  if (tid < 128){
    float a1=b1[tid];
    for (int m=0;m<HH;m++) a1+=sxm[m]*w1T[m*128+tid];
    stt[tid]=gelu_f(a1);
  }
  __syncthreads();
  if (tid < 128){
    float a2=b2[tid];
    for (int m=0;m<HH;m++) a2+=stt[m]*w2T[m*128+tid];
    sx[tid] = sx[tid] + a2;      // final eig row, LDS only
  }
  __syncthreads();
  // ---- dec (exact k_dec serial-h arithmetic) ----
  if (tid < 4){
    float acc = db[tid];
    const float* wr = dW + tid*HH;
    for (int h2=0;h2<HH;h2++) acc += sx[h2]*wr[h2];
    int idx=(b*NHD+tid)*NN+qi;
    newe[idx]=acc; outp[8+idx]=acc;
  }
}

// ---------------- bases: filters computed inline (k_filters dispatch + 2MB filt
// round-trip eliminated). f4[k] = sum_m u[n][m]*newe[k][m]*u[pr][m], sequential m
// (same summation order as the old k_filters). u is L2-resident; cn reads are
// lane-uniform broadcasts.
__global__ __launch_bounds__(256) void k_fe2(const float* __restrict__ u,
    const float* __restrict__ newe,
    const float* __restrict__ w1g, const float* __restrict__ b1g,
    const ushortt* __restrict__ w2bf, const float* __restrict__ b2g,
    const int* __restrict__ length,
    bf16* __restrict__ bases){
  int blk = blockIdx.x;
  int bi = blk >> 1;
  int r0 = (blk & 1)*64;
  int b = bi >> 7;
  int nloc = bi & 127;
  int len = length[b];
  if (nloc >= len || r0 >= len) return;
  int tid = threadIdx.x;
  int lane = tid & 63, w = tid >> 6, quad = lane >> 4, l15 = lane & 15;
  int pr = r0 + w*16 + l15;
  __shared__ alignas(16) ushortt sW2[128*136];
  __shared__ float w1p[128*8];
  __shared__ float b2s[128];
  __shared__ float cn[4][128];
  for (int idx = tid; idx < 2048; idx += 256){
    int r = idx >> 4, cb = idx & 15;
    *(uint4*)&sW2[r*136 + cb*8] = *(const uint4*)&w2bf[r*128 + cb*8];
  }
  for (int idx = tid; idx < 1024; idx += 256){
    int r = idx >> 3, c = idx & 7;
    w1p[idx] = (c==0) ? b1g[r] : (c<=5 ? w1g[r*5 + c-1] : 0.f);
  }
  for (int idx = tid; idx < 512; idx += 256){
    int k = idx >> 7, m = idx & 127;
    cn[k][m] = u[(b*NN+nloc)*NN + m] * newe[(b*NHD+k)*NN + m];
  }
  if (tid < 128) b2s[tid] = b2g[tid];
  __syncthreads();
  bool wact = (r0 + w*16) < len;
  f32x4 acc[8];
  #pragma unroll
  for (int nt=0;nt<8;nt++) acc[nt] = (f32x4){0.f,0.f,0.f,0.f};
  if (wact){
    // inline filter row: 4 dots over m, sequential order
    float f0=0.f, f1=0.f, f2v=0.f, f3=0.f;
    const float4* ur = (const float4*)(u + ((size_t)b*NN + pr)*NN);
    for (int m4 = 0; m4 < 32; m4++){
      float4 uv = ur[m4];
      int m = m4*4;
      f0 += cn[0][m]*uv.x; f0 += cn[0][m+1]*uv.y; f0 += cn[0][m+2]*uv.z; f0 += cn[0][m+3]*uv.w;
      f1 += cn[1][m]*uv.x; f1 += cn[1][m+1]*uv.y; f1 += cn[1][m+2]*uv.z; f1 += cn[1][m+3]*uv.w;
      f2v += cn[2][m]*uv.x; f2v += cn[2][m+1]*uv.y; f2v += cn[2][m+2]*uv.z; f2v += cn[2][m+3]*uv.w;
      f3 += cn[3][m]*uv.x; f3 += cn[3][m+1]*uv.y; f3 += cn[3][m+2]*uv.z; f3 += cn[3][m+3]*uv.w;
    }
    float dg = (pr == nloc) ? 1.0f : 0.0f;
    for (int kk = 0; kk < 128; kk += 32){
      bf16x8 af;
      #pragma unroll
      for (int j=0;j<8;j++){
        int m = kk + quad*8 + j;
        const float4 wa = *(const float4*)&w1p[m*8];
        const float2 wb = *(const float2*)&w1p[m*8+4];
        float a = wa.x + wa.y*dg + wa.z*f0 + wa.w*f1 + wb.x*f2v + wb.y*f3;
        af[j] = (short)f2us(gelu_fe(a));
      }
      #pragma unroll
      for (int nt=0;nt<8;nt++){
        bf16x8 bfr = *(const bf16x8*)&sW2[(nt*16+l15)*136 + kk + quad*8];
        acc[nt] = __builtin_amdgcn_mfma_f32_16x16x32_bf16(af, bfr, acc[nt], 0, 0, 0);
      }
    }
  }
  __syncthreads();
  ushortt* sT = sW2;
  if (wact){
    #pragma unroll
    for (int nt=0;nt<8;nt++){
      int h = nt*16 + l15;
      float bb = b2s[h];
      #pragma unroll
      for (int reg=0;reg<4;reg++){
        int lr = w*16 + quad*4 + reg;
        sT[lr*132 + h] = f2us(gelu_fe(acc[nt][reg] + bb));
      }
    }
  }
  __syncthreads();
  int rmax = len - r0; if (rmax > 64) rmax = 64;
  ushort4* gout = (ushort4*)(bases + (size_t)bi*16384 + r0*128);
  for (int idx = tid; idx < rmax*32; idx += 256){
    int row = idx >> 5, seg = idx & 31;
    gout[idx] = *(const ushort4*)&sT[row*132 + seg*4];
  }
}

// ---------------- message passing (R4-proven kernels) ----------------
// gs layout per layer (stride 2560): [bank0..7][sum1(128)|sq1(128)] + 2048:[sum2|sq2]

__global__ __launch_bounds__(256) void k_xwl2(const float* __restrict__ xfprev,
    const float* __restrict__ t2, const float* __restrict__ gsum2p,
    const float* __restrict__ gsq2p, const float* __restrict__ g2p,
    const float* __restrict__ bb2p, const int* __restrict__ length, int prevapply,
    const ushortt* __restrict__ wbfl, float* __restrict__ xfB,
    float* __restrict__ xfW){
  int blk = blockIdx.x;
  int b = blk >> 2, rq = blk & 3;
  int tid = threadIdx.x;
  int lane = tid & 63, w = tid >> 6, quad = lane >> 4, l15 = lane & 15;
  __shared__ alignas(16) ushortt sA[32*136];
  __shared__ float smu[128], sistd[128], sg[128], sbb[128];
  if (prevapply && tid < 128){
    float cnt = 0.f;
    for (int q2=0;q2<BB;q2++) cnt += (float)length[q2];
    float mu = gsum2p[tid]/cnt;
    float var = gsq2p[tid]/cnt - mu*mu;
    smu[tid]=mu; sistd[tid]=rsqrtf(fmaxf(var,0.0f)+EPSV);
    sg[tid]=g2p[tid]; sbb[tid]=bb2p[tid];
  }
  __syncthreads();
  for (int idx = tid; idx < 1024; idx += 256){
    int r = idx >> 5, c = idx & 31;
    int gr = b*128 + rq*32 + r;
    float4 xv = ((const float4*)xfprev)[gr*32 + c];
    if (prevapply){
      float4 tv = ((const float4*)t2)[gr*32 + c];
      int f0 = c*4;
      xv.x += fmaxf((tv.x-smu[f0+0])*sistd[f0+0]*sg[f0+0]+sbb[f0+0], 0.f);
      xv.y += fmaxf((tv.y-smu[f0+1])*sistd[f0+1]*sg[f0+1]+sbb[f0+1], 0.f);
      xv.z += fmaxf((tv.z-smu[f0+2])*sistd[f0+2]*sg[f0+2]+sbb[f0+2], 0.f);
      xv.w += fmaxf((tv.w-smu[f0+3])*sistd[f0+3]*sg[f0+3]+sbb[f0+3], 0.f);
      ((float4*)xfB)[gr*32 + c] = xv;
    }
    ushort4 o;
    o.x=f2us(xv.x); o.y=f2us(xv.y); o.z=f2us(xv.z); o.w=f2us(xv.w);
    *(ushort4*)&sA[r*136 + c*4] = o;
  }
  __syncthreads();
  f32x4 acc[2][2];
  #pragma unroll
  for (int mt=0;mt<2;mt++)
    #pragma unroll
    for (int nt=0;nt<2;nt++) acc[mt][nt] = (f32x4){0.f,0.f,0.f,0.f};
  #pragma unroll
  for (int kk = 0; kk < 128; kk += 32){
    bf16x8 af[2], bfr[2];
    #pragma unroll
    for (int mt=0;mt<2;mt++) af[mt] = *(const bf16x8*)&sA[(mt*16+l15)*136 + kk + quad*8];
    #pragma unroll
    for (int nt=0;nt<2;nt++) bfr[nt] = *(const bf16x8*)&wbfl[((w*2+nt)*16+l15)*128 + kk + quad*8];
    #pragma unroll
    for (int mt=0;mt<2;mt++)
      #pragma unroll
      for (int nt=0;nt<2;nt++)
        acc[mt][nt] = __builtin_amdgcn_mfma_f32_16x16x32_bf16(af[mt], bfr[nt], acc[mt][nt], 0, 0, 0);
  }
  #pragma unroll
  for (int mt=0;mt<2;mt++)
    #pragma unroll
    for (int nt=0;nt<2;nt++){
      int h = (w*2+nt)*16 + l15;
      #pragma unroll
      for (int reg=0;reg<4;reg++){
        int prr = rq*32 + mt*16 + quad*4 + reg;
        xfW[(b*128 + prr)*128 + h] = acc[mt][nt][reg];
      }
    }
}

// per-edge elementwise + FUSED g1 GEMM + BN1 partial stats (R4-proven)
__global__ __launch_bounds__(512) void k_edge(const float* __restrict__ xfin, float* __restrict__ xfout,
    const bf16* __restrict__ bases, const float* __restrict__ xfW,
    const float* __restrict__ bondWl, const int* __restrict__ ef,
    const int* __restrict__ length,
    const float* __restrict__ w1t, const float* __restrict__ bias1,
    float* __restrict__ t1, float* __restrict__ gst){
  int bj = blockIdx.x; int b = bj >> 7, j = bj & 127;
  int len = length[b];
  int tid = threadIdx.x; int h = tid & 127, ih = tid >> 7;   // ih in 0..3
  __shared__ float sBW[10][128];
  __shared__ int sEf[128];
  __shared__ float part[4][128];
  for (int idx = tid; idx < 1280; idx += 512) sBW[idx>>7][idx&127] = bondWl[idx];
  if (tid < 128) sEf[tid] = ef[(b*NN + tid)*NN + j];
  __syncthreads();
  float agg = 0.f;
  if (j < len){
    const float* xwb = xfW + b*NN*HH + h;
    const bf16* bb = bases + ((size_t)b*NN + j)*NN*HH + h;
    for (int i = ih; i < len; i += 4){
      float vv = gelu_h(xwb[i*128] + sBW[sEf[i]][h]);
      agg += vv * b2f(bb[i*128]);
    }
  }
  part[ih][h] = agg; __syncthreads();
  if (tid < 128){
    int o = (b*NN + j)*HH + tid;
    float xrow = xfin[o] + part[0][tid] + part[1][tid] + part[2][tid] + part[3][tid];
    xfout[o] = xrow;
    part[0][tid] = xrow;
  }
  __syncthreads();
  float acc = (ih==0) ? bias1[h] : 0.f;
  {
    const float* wcol = w1t + h;
    int m0 = ih*32;
    for (int m = m0; m < m0+32; m++) acc += part[0][m]*wcol[m*128];
  }
  float* red = &sBW[0][0];
  __syncthreads();
  red[ih*128 + h] = acc; __syncthreads();
  if (tid < 128){
    float t1v = red[tid] + red[128+tid] + red[256+tid] + red[384+tid];
    t1[(b*NN + j)*HH + tid] = t1v;
    if (j < len){
      int bank = bj & 7;
      atomicAdd(&gst[bank*256 + tid], t1v);
      atomicAdd(&gst[bank*256 + 128 + tid], t1v*t1v);
    }
  }
}

// finalize BN1 (sum 8 banks) + relu + g2 GEMM + partial BN2 stats (R4-proven)
__global__ __launch_bounds__(256) void k_g2s(const float* __restrict__ t1,
    const float* __restrict__ gstL,
    const float* __restrict__ g1, const float* __restrict__ bb1,
    const float* __restrict__ w2t, const float* __restrict__ bias2,
    const int* __restrict__ length, float* __restrict__ t2){
  int blk = blockIdx.x; int tid = threadIdx.x;
  int f = tid & 127, rh = tid >> 7;
  __shared__ float sy[4][128];
  __shared__ float red1[2][128], red2[2][128];
  int r0 = blk*4;
  float cnt = 0.f;
  for (int b=0;b<BB;b++) cnt += (float)length[b];
  float su = 0.f, sq = 0.f;
  #pragma unroll
  for (int k=0;k<8;k++){ su += gstL[k*256 + f]; sq += gstL[k*256 + 128 + f]; }
  float mu = su/cnt;
  float var = sq/cnt - mu*mu;
  float istd = rsqrtf(fmaxf(var,0.0f)+EPSV);
  float gg = g1[f], bbv = bb1[f];
  for (int idx = tid; idx < 512; idx += 256){
    int r = idx >> 7;
    float x = t1[(r0+r)*128 + f];
    float y = (x-mu)*istd*gg + bbv;
    sy[r][f] = fmaxf(y, 0.0f);
  }
  __syncthreads();
  float bsv = bias2[f];
  float s=0.f, s2=0.f;
  for (int rr = rh*2; rr < rh*2+2; rr++){
    int rg = r0 + rr; int b = rg >> 7, n = rg & 127;
    float acc = bsv;
    for (int m=0;m<128;m++) acc += sy[rr][m]*w2t[m*128+f];
    t2[rg*128+f] = acc;
    if (n < length[b]){ s += acc; s2 += acc*acc; }
  }
  red1[rh][f]=s; red2[rh][f]=s2; __syncthreads();
  if (tid < 128){
    atomicAdd((float*)&gstL[2048 + tid], red1[0][tid]+red1[1][tid]);
    atomicAdd((float*)&gstL[2048 + 128 + tid], red2[0][tid]+red2[1][tid]);
  }
}

// final BN2-apply fused into pooling + linear head (R4-proven)
__global__ void k_pool2(const float* __restrict__ xf, const float* __restrict__ t2,
                        const float* __restrict__ gsum2, const float* __restrict__ gsq2,
                        const float* __restrict__ g2, const float* __restrict__ bb2,
                        const int* __restrict__ length,
                        const float* lw, const float* lb, float* __restrict__ outp){
  int b = blockIdx.x, tid=threadIdx.x;
  int len = length[b];
  float cnt = 0.f;
  for (int q2=0;q2<BB;q2++) cnt += (float)length[q2];
  float mu = gsum2[tid]/cnt;
  float var = gsq2[tid]/cnt - mu*mu;
  float istd = rsqrtf(fmaxf(var,0.0f)+EPSV);
  float gg = g2[tid], bbv = bb2[tid];
  float s=0.f;
  for (int n2=0;n2<len;n2++){
    int o = (b*NN+n2)*HH+tid;
    float x = xf[o] + fmaxf((t2[o]-mu)*istd*gg+bbv, 0.0f);
    s += x;
  }
  s /= (float)len;
  __shared__ float red[128];
  red[tid]=s*lw[tid]; __syncthreads();
  for (int st=64;st>0;st>>=1){ if(tid<st) red[tid]+=red[tid+st]; __syncthreads(); }
  if (tid==0) outp[b]=red[0]+lb[0];
}

// ---------------- host ----------------

extern "C" void kernel_launch(void* const* d_in, const int* in_sizes, int n_in,
                              void* d_out, int out_size, void* d_ws, size_t ws_size,
                              hipStream_t stream) {
  (void)in_sizes; (void)n_in; (void)out_size; (void)ws_size;
  const float* e        = (const float*)d_in[0];
  const float* u        = (const float*)d_in[1];
  const float* atom_emb = (const float*)d_in[2];
  const float* bond_emb = (const float*)d_in[3];
  const float* eigw_W   = (const float*)d_in[4];
  const float* eigw_b   = (const float*)d_in[5];
  const float* mng      = (const float*)d_in[6];
  const float* mnb      = (const float*)d_in[7];
  const float* qkvW     = (const float*)d_in[8];
  const float* qkvb     = (const float*)d_in[9];
  const float* outW     = (const float*)d_in[10];
  const float* outb     = (const float*)d_in[11];
  const float* fng      = (const float*)d_in[12];
  const float* fnb      = (const float*)d_in[13];
  const float* ffn1W    = (const float*)d_in[14];
  const float* ffn1b    = (const float*)d_in[15];
  const float* ffn2W    = (const float*)d_in[16];
  const float* ffn2b    = (const float*)d_in[17];
  const float* decW     = (const float*)d_in[18];
  const float* decb     = (const float*)d_in[19];
  const float* fe1W     = (const float*)d_in[20];
  const float* fe1b     = (const float*)d_in[21];
  const float* fe2W     = (const float*)d_in[22];
  const float* fe2b     = (const float*)d_in[23];
  const float* preW     = (const float*)d_in[24];
  const float* preb     = (const float*)d_in[25];
  const float* f1W      = (const float*)d_in[26];
  const float* f1b      = (const float*)d_in[27];
  const float* bn1g     = (const float*)d_in[28];
  const float* bn1b     = (const float*)d_in[29];
  const float* f2W      = (const float*)d_in[30];
  const float* f2b      = (const float*)d_in[31];
  const float* bn2g     = (const float*)d_in[32];
  const float* bn2b     = (const float*)d_in[33];
  const float* linW     = (const float*)d_in[34];
  const float* linb     = (const float*)d_in[35];
  const int* nodef      = (const int*)d_in[36];
  const int* edgef      = (const int*)d_in[37];
  const int* length     = (const int*)d_in[38];

  float* outp = (float*)d_out;   // h[8] ++ new_e[4096] ++ attn[524288], f32

  char* p = (char*)d_ws;
  auto alloc = [&](size_t bytes)->void*{ void* r=(void*)p; p += (bytes+255)&~(size_t)255; return r; };
  const int TOK = BB*NN*HH;           // 131072
  float* eig   = (float*)alloc(TOK*4);
  float* q     = (float*)alloc(TOK*4);
  float* kT    = (float*)alloc(TOK*4);
  float* v     = (float*)alloc(TOK*4);
  float* newe  = (float*)alloc(BB*NHD*NN*4);
  bf16*  bases = (bf16*) alloc((size_t)BB*NN*NN*HH*2);
  float* xf0   = (float*)alloc(TOK*4);
  float* xfB   = (float*)alloc(TOK*4);
  float* xfC   = (float*)alloc(TOK*4);
  float* xfD   = (float*)alloc(TOK*4);
  float* t1    = (float*)alloc(TOK*4);
  float* t2    = (float*)alloc(TOK*4);
  float* xfW   = (float*)alloc(TOK*4);
  float* gs    = (float*)alloc(10240*4);         // 4 layers x 2560
  ushortt* wbf = (ushortt*)alloc(81920*2);
  float* eigWT = (float*)alloc(16512*4);
  float* qkvWT = (float*)alloc(49152*4);
  float* outWT = (float*)alloc(16384*4);
  float* ffn1WT= (float*)alloc(16384*4);
  float* ffn2WT= (float*)alloc(16384*4);
  float* f1WT  = (float*)alloc(65536*4);
  float* f2WT  = (float*)alloc(65536*4);
  float* bondWall = (float*)alloc(5120*4);

  k_prep<<<512, 256, 0, stream>>>(fe2W, preW, eigw_W, qkvW, outW, ffn1W, ffn2W,
                                  f1W, f2W, atom_emb, nodef, bond_emb, preb,
                                  wbf, gs, xf0, eigWT, qkvWT, outWT, ffn1WT,
                                  ffn2WT, f1WT, f2WT, bondWall);

  // front end (3 dispatches, was 5)
  k_fe_a<<<BB*NN, 128, 0, stream>>>(e, eigWT, eigw_b, mng, mnb, qkvWT, qkvb, eig, q, kT, v);
  k_attc<<<BB*NN, 512, 0, stream>>>(q, kT, v, eig, length,
                                    outWT, outb, fng, fnb,
                                    ffn1WT, ffn1b, ffn2WT, ffn2b,
                                    decW, decb, newe, outp);

  // bases (1 dispatch, was 2 — filters inlined)
  k_fe2<<<2*BB*NN, 256, 0, stream>>>(u, newe, fe1W, fe1b, wbf, fe2b, length, bases);

  // message passing: 3 kernels/layer (edge+g1 fused)
  const float* xfprev = xf0;
  float* xfcur = xfC;
  for (int l=0;l<LAY;l++){
    const ushortt* wbfl = wbf + 16384 + l*16384;
    float* gsl = gs + l*2560;
    float* gsp = gs + (l-1)*2560;
    k_xwl2<<<BB*4, 256, 0, stream>>>(xfprev, t2,
                                   (l>0)? gsp+2048 : gs, (l>0)? gsp+2048+128 : gs,
                                   bn2g + (l>0? (l-1)*HH:0), bn2b + (l>0? (l-1)*HH:0),
                                   length, (l>0)?1:0,
                                   wbfl, xfB, xfW);
    const float* xin = (l==0)? xf0 : xfB;
    k_edge<<<BB*NN, 512, 0, stream>>>(xin, xfcur, bases, xfW, bondWall + l*1280,
                                      edgef, length,
                                      f1WT + l*16384, f1b + l*HH, t1, gsl);
    k_g2s<<<256, 256, 0, stream>>>(t1, gsl, bn1g + l*HH, bn1b + l*HH,
                                   f2WT + l*16384, f2b + l*HH, length, t2);
    xfprev = xfcur;
    xfcur = (xfcur == xfC) ? xfD : xfC;
  }
  // final: BN2(layer3) applied inside pool (xfprev holds layer-3 output)
  k_pool2<<<BB, 128, 0, stream>>>(xfprev, t2, gs+3*2560+2048, gs+3*2560+2048+128,
                                  bn2g + 3*HH, bn2b + 3*HH, length, linW, linb, outp);
}

// Round 8
// 399.405 us; speedup vs baseline: 1.2679x; 1.0262x over previous
//
#include <hip/hip_runtime.h>
#include <hip/hip_bf16.h>
#include <math.h>

#define BB 8
#define NN 128
#define HH 128
#define NHD 4
#define DHD 32
#define LAY 4
#define EPSV 1e-5f

typedef __hip_bfloat16 bf16;
typedef unsigned short ushortt;
typedef short bf16x8 __attribute__((ext_vector_type(8)));
typedef float f32x4 __attribute__((ext_vector_type(4)));

__device__ __forceinline__ float b2f(bf16 x){ return __bfloat162float(x); }
__device__ __forceinline__ bf16 f2b(float x){ return __float2bfloat16(x); }
__device__ __forceinline__ ushortt f2us(float x){ bf16 b=__float2bfloat16(x); return *(ushortt*)&b; }
__device__ __forceinline__ float gelu_f(float x){ return 0.5f*x*(1.0f+erff(x*0.7071067811865476f)); }
// fast tanh-gelu — h-path serial loops only (k_edge); measured win there
__device__ __forceinline__ float gelu_h(float x){
  float t = 0.7978845608028654f*x*(1.0f + 0.044715f*x*x);
  float e = __expf(2.0f*t);
  float th = 1.0f - 2.0f/(e + 1.0f);
  return 0.5f*x*(1.0f + th);
}
// branch-free A&S 7.1.26 erf (|err| <= 1.5e-7)
__device__ __forceinline__ float erf_fast(float x){
  float ax = fabsf(x);
  float t = __builtin_amdgcn_rcpf(__builtin_fmaf(0.3275911f, ax, 1.0f));
  float p = __builtin_fmaf(1.061405429f, t, -1.453152027f);
  p = __builtin_fmaf(p, t, 1.421413741f);
  p = __builtin_fmaf(p, t, -0.284496736f);
  p = __builtin_fmaf(p, t, 0.254829592f);
  p = p*t;
  float e = __expf(-ax*ax);
  float y = __builtin_fmaf(-p, e, 1.0f);
  return __builtin_copysignf(y, x);
}
__device__ __forceinline__ float gelu_fe(float x){
  return 0.5f*x*(1.0f + erf_fast(x*0.7071067811865476f));
}

// ---------------- prep ----------------

__global__ __launch_bounds__(256) void k_prep(const float* __restrict__ fe2W,
    const float* __restrict__ preW, const float* __restrict__ eigW,
    const float* __restrict__ qkvW, const float* __restrict__ outW,
    const float* __restrict__ ffn1W, const float* __restrict__ ffn2W,
    const float* __restrict__ f1W, const float* __restrict__ f2W,
    const float* __restrict__ aemb, const int* __restrict__ nf,
    const float* __restrict__ bemb, const float* __restrict__ preb,
    ushortt* __restrict__ wbf, float* __restrict__ gs, float* __restrict__ xf0,
    float* __restrict__ eigWT, float* __restrict__ qkvWT, float* __restrict__ outWT,
    float* __restrict__ ffn1WT, float* __restrict__ ffn2WT,
    float* __restrict__ f1WT, float* __restrict__ f2WT,
    float* __restrict__ bondWall){
  int idx = blockIdx.x*256 + threadIdx.x;    // grid covers 131072
  if (idx < 10240) gs[idx] = 0.f;            // 4 layers x 2560
  if (idx < 81920){
    float v = (idx < 16384) ? fe2W[idx] : preW[idx - 16384];
    wbf[idx] = f2us(v);
  }
  if (idx < 131072){
    int node = idx >> 7, h2 = idx & 127;
    xf0[idx] = aemb[nf[node]*HH + h2];
  }
  if (idx < 16512){ int o = idx/129, kq = idx - o*129; eigWT[kq*128+o] = eigW[idx]; }
  if (idx < 49152){ int o = idx>>7, m = idx&127; qkvWT[m*384+o] = qkvW[idx]; }
  if (idx < 16384){ int o = idx>>7, m = idx&127;
    outWT[m*128+o]  = outW[idx];
    ffn1WT[m*128+o] = ffn1W[idx];
    ffn2WT[m*128+o] = ffn2W[idx];
  }
  if (idx < 65536){ int l = idx>>14, r = idx&16383; int o = r>>7, m = r&127;
    f1WT[l*16384 + m*128+o] = f1W[idx];
    f2WT[l*16384 + m*128+o] = f2W[idx];
  }
  if (idx < 5120){
    int l = idx / 1280; int r = idx - l*1280; int e2 = r >> 7; int hcol = r & 127;
    const float* br = bemb + e2*128;
    const float* wr = preW + l*16384 + hcol*128;
    float acc = preb[l*128 + hcol];
    for (int m=0;m<128;m++) acc += br[m]*wr[m];
    bondWall[idx] = acc;
  }
}

// ---------------- front end ----------------

__global__ void k_fe_a(const float* __restrict__ e, const float* __restrict__ eigWT,
                       const float* __restrict__ eigb, const float* __restrict__ g,
                       const float* __restrict__ bt, const float* __restrict__ qkvWT,
                       const float* __restrict__ qkvb,
                       float* __restrict__ eigout, float* __restrict__ q,
                       float* __restrict__ kT, float* __restrict__ v){
  int row = blockIdx.x; int tid = threadIdx.x;
  int b = row >> 7, n = row & 127;
  __shared__ float ee[129]; __shared__ float buf[128]; __shared__ float xm[128];
  float ev = e[row];
  if (tid < 64){
    float dv = expf(-0.1439115683121279f * (float)tid);
    float pe = ev * 100.0f * dv;
    ee[1+tid] = sinf(pe);
    ee[65+tid] = cosf(pe);
  }
  if (tid == 0) ee[0] = ev;
  __syncthreads();
  float x = eigb[tid];
  for (int k2=0;k2<129;k2++) x += ee[k2]*eigWT[k2*128+tid];
  eigout[row*HH+tid] = x;
  buf[tid]=x; __syncthreads();
  for (int s2=64;s2>0;s2>>=1){ if(tid<s2) buf[tid]+=buf[tid+s2]; __syncthreads(); }
  float mean = buf[0]*(1.0f/128.0f); __syncthreads();
  float d = x-mean; buf[tid]=d*d; __syncthreads();
  for (int s2=64;s2>0;s2>>=1){ if(tid<s2) buf[tid]+=buf[tid+s2]; __syncthreads(); }
  float var = buf[0]*(1.0f/128.0f);
  xm[tid] = d*rsqrtf(var+EPSV)*g[tid]+bt[tid];
  __syncthreads();
  #pragma unroll
  for (int s3=0;s3<3;s3++){
    float acc = qkvb[s3*HH+tid];
    const float* wt = qkvWT + s3*HH + tid;
    for (int m=0;m<HH;m++) acc += xm[m]*wt[m*384];
    if (s3==0) q[row*HH+tid]=acc;
    else if (s3==1) kT[b*16384 + tid*128 + n]=acc;
    else v[row*HH+tid]=acc;
  }
}

// fused attention + out-proj + LN + FFN + dec per (b,qi): block-local, exact
// per-item arithmetic of the R4 k_attn/k_fe_c/k_dec kernels.
__global__ __launch_bounds__(512) void k_attc(const float* __restrict__ q,
    const float* __restrict__ kT, const float* __restrict__ v,
    const float* __restrict__ eig, const int* __restrict__ length,
    const float* __restrict__ outWT, const float* __restrict__ outb,
    const float* __restrict__ fng, const float* __restrict__ fnb,
    const float* __restrict__ w1T, const float* __restrict__ b1,
    const float* __restrict__ w2T, const float* __restrict__ b2,
    const float* __restrict__ dW, const float* __restrict__ db,
    float* __restrict__ newe, float* __restrict__ outp){
  int row = blockIdx.x; int b = row>>7, qi = row&127;
  int tid = threadIdx.x;
  int hg = tid>>7, lt = tid&127;
  int len = length[b];
  __shared__ float qv[4][DHD];
  __shared__ float red[4][128];
  __shared__ float satt[4][128];
  __shared__ float sc[128], sbuf[128], sxm[128], stt[128], sx[128];
  // ---- attention (4 heads in lockstep; exact k_attn arithmetic) ----
  if (lt < DHD) qv[hg][lt] = q[(b*NN+qi)*HH + hg*DHD + lt];
  __syncthreads();
  float s = -1e30f;
  if (lt < len){
    const float* kr = kT + b*16384 + hg*DHD*128 + lt;
    float scr=0.f;
    for (int d2=0; d2<DHD; d2++) scr += qv[hg][d2]*kr[d2*128];
    s = scr * 0.17677669529663687f;
  }
  red[hg][lt]=s; __syncthreads();
  for (int st=64;st>0;st>>=1){ if(lt<st) red[hg][lt]=fmaxf(red[hg][lt],red[hg][lt+st]); __syncthreads(); }
  float mx = red[hg][0]; __syncthreads();
  float pp = (lt<len)? expf(s-mx):0.0f;
  red[hg][lt]=pp; __syncthreads();
  for (int st=64;st>0;st>>=1){ if(lt<st) red[hg][lt]+=red[hg][lt+st]; __syncthreads(); }
  float a = pp / red[hg][0];
  satt[hg][lt] = a;
  outp[4104 + ((b*NHD+hg)*NN+qi)*NN + lt] = a;
  __syncthreads();
  // ---- ctx + out-proj + LN (exact k_fe_c arithmetic, tid<128) ----
  if (tid < 128){
    int hd = tid>>5;
    float acc=0.f;
    for (int j=0;j<NN;j++) acc += satt[hd][j]*v[(b*NN+j)*HH+tid];
    sc[tid]=acc;
  }
  __syncthreads();
  if (tid < 128){
    float o = outb[tid];
    for (int m=0;m<HH;m++) o += sc[m]*outWT[m*128+tid];
    float x = eig[row*HH+tid] + o;
    sx[tid] = x; sbuf[tid] = x;
  }
  __syncthreads();
  for (int s2=64;s2>0;s2>>=1){ if(tid<s2) sbuf[tid]+=sbuf[tid+s2]; __syncthreads(); }
  float mean = sbuf[0]*(1.f/128.f); __syncthreads();
  if (tid < 128){ float d = sx[tid]-mean; sbuf[tid]=d*d; }
  __syncthreads();
  for (int s2=64;s2>0;s2>>=1){ if(tid<s2) sbuf[tid]+=sbuf[tid+s2]; __syncthreads(); }
  float var = sbuf[0]*(1.f/128.f);
  if (tid < 128){
    float d = sx[tid]-mean;
    sxm[tid] = d*rsqrtf(var+EPSV)*fng[tid]+fnb[tid];
  }
  __syncthreads();
  if (tid < 128){
    float a1=b1[tid];
    for (int m=0;m<HH;m++) a1+=sxm[m]*w1T[m*128+tid];
    stt[tid]=gelu_f(a1);
  }
  __syncthreads();
  if (tid < 128){
    float a2=b2[tid];
    for (int m=0;m<HH;m++) a2+=stt[m]*w2T[m*128+tid];
    sx[tid] = sx[tid] + a2;      // final eig row, LDS only
  }
  __syncthreads();
  // ---- dec (exact k_dec serial-h arithmetic) ----
  if (tid < 4){
    float acc = db[tid];
    const float* wr = dW + tid*HH;
    for (int h2=0;h2<HH;h2++) acc += sx[h2]*wr[h2];
    int idx=(b*NHD+tid)*NN+qi;
    newe[idx]=acc; outp[8+idx]=acc;
  }
}

// ---------------- bases: inline filters + XOR-swizzled weight LDS ----------------
// sW2 swizzle (T2): row stride 128 ushorts (256B, no pad); the 16B chunk at
// logical chunk index c of row r is stored at chunk index c ^ (r&15).
// Staging (ushort units): (cb*8) ^ ((r&15)<<3).  MFMA read (BUGFIX vs R7: kk is
// already in ushort units — was kk*2, which read past the row/array and pulled
// NaN-pattern garbage): off = (kk + quad*8) ^ (l15<<3), where rowb&15 == l15.
// Bank check: stored chunk s=(kk/8+quad)^l15; byte=rowb*256+16s; bank=4s%32;
// 64 lanes spread 8 per s-mod-8 class -> uniform BW-floor access, no conflict.
__global__ __launch_bounds__(256) void k_fe2(const float* __restrict__ u,
    const float* __restrict__ newe,
    const float* __restrict__ w1g, const float* __restrict__ b1g,
    const ushortt* __restrict__ w2bf, const float* __restrict__ b2g,
    const int* __restrict__ length,
    bf16* __restrict__ bases){
  int blk = blockIdx.x;
  int bi = blk >> 1;
  int r0 = (blk & 1)*64;
  int b = bi >> 7;
  int nloc = bi & 127;
  int len = length[b];
  if (nloc >= len || r0 >= len) return;
  int tid = threadIdx.x;
  int lane = tid & 63, w = tid >> 6, quad = lane >> 4, l15 = lane & 15;
  int pr = r0 + w*16 + l15;
  __shared__ alignas(16) ushortt sW2[128*128];   // swizzled; reused as sT later
  __shared__ float w1a[128*4];   // b1, w0, w1, w2 (float4-aligned)
  __shared__ float w1b[128*2];   // w3, w4 (float2-aligned)
  __shared__ float b2s[128];
  __shared__ float cn[4][128];
  for (int idx = tid; idx < 2048; idx += 256){
    int r = idx >> 4, cb = idx & 15;
    *(uint4*)&sW2[r*128 + ((cb*8) ^ ((r&15)<<3))] = *(const uint4*)&w2bf[r*128 + cb*8];
  }
  if (tid < 128){
    w1a[tid*4+0] = b1g[tid];
    w1a[tid*4+1] = w1g[tid*5+0];
    w1a[tid*4+2] = w1g[tid*5+1];
    w1a[tid*4+3] = w1g[tid*5+2];
    w1b[tid*2+0] = w1g[tid*5+3];
    w1b[tid*2+1] = w1g[tid*5+4];
    b2s[tid] = b2g[tid];
  }
  for (int idx = tid; idx < 512; idx += 256){
    int k = idx >> 7, m = idx & 127;
    cn[k][m] = u[(b*NN+nloc)*NN + m] * newe[(b*NHD+k)*NN + m];
  }
  __syncthreads();
  bool wact = (r0 + w*16) < len;
  f32x4 acc[8];
  #pragma unroll
  for (int nt=0;nt<8;nt++) acc[nt] = (f32x4){0.f,0.f,0.f,0.f};
  if (wact){
    // quad-split filter dot: quad covers m in [quad*32, quad*32+32)
    float f0=0.f, f1=0.f, f2v=0.f, f3=0.f;
    const float4* ur = (const float4*)(u + ((size_t)b*NN + pr)*NN);
    for (int m4 = quad*8; m4 < quad*8+8; m4++){
      float4 uv = ur[m4];
      int m = m4*4;
      f0 += cn[0][m]*uv.x; f0 += cn[0][m+1]*uv.y; f0 += cn[0][m+2]*uv.z; f0 += cn[0][m+3]*uv.w;
      f1 += cn[1][m]*uv.x; f1 += cn[1][m+1]*uv.y; f1 += cn[1][m+2]*uv.z; f1 += cn[1][m+3]*uv.w;
      f2v += cn[2][m]*uv.x; f2v += cn[2][m+1]*uv.y; f2v += cn[2][m+2]*uv.z; f2v += cn[2][m+3]*uv.w;
      f3 += cn[3][m]*uv.x; f3 += cn[3][m+1]*uv.y; f3 += cn[3][m+2]*uv.z; f3 += cn[3][m+3]*uv.w;
    }
    // reduce across quads (lanes l^16, l^32): (q0+q1)+(q2+q3)
    f0 += __shfl_xor(f0, 16, 64);  f0 += __shfl_xor(f0, 32, 64);
    f1 += __shfl_xor(f1, 16, 64);  f1 += __shfl_xor(f1, 32, 64);
    f2v += __shfl_xor(f2v, 16, 64); f2v += __shfl_xor(f2v, 32, 64);
    f3 += __shfl_xor(f3, 16, 64);  f3 += __shfl_xor(f3, 32, 64);
    float dg = (pr == nloc) ? 1.0f : 0.0f;
    for (int kk = 0; kk < 128; kk += 32){
      bf16x8 af;
      #pragma unroll
      for (int j=0;j<8;j++){
        int m = kk + quad*8 + j;
        const float4 wa = *(const float4*)&w1a[m*4];
        const float2 wb = *(const float2*)&w1b[m*2];
        float a = wa.x + wa.y*dg + wa.z*f0 + wa.w*f1 + wb.x*f2v + wb.y*f3;
        af[j] = (short)f2us(gelu_fe(a));
      }
      #pragma unroll
      for (int nt=0;nt<8;nt++){
        int rowb = nt*16 + l15;
        int off = (kk + quad*8) ^ (l15 << 3);   // ushort units; rowb&15 == l15
        bf16x8 bfr = *(const bf16x8*)&sW2[rowb*128 + off];
        acc[nt] = __builtin_amdgcn_mfma_f32_16x16x32_bf16(af, bfr, acc[nt], 0, 0, 0);
      }
    }
  }
  __syncthreads();
  ushortt* sT = sW2;
  if (wact){
    #pragma unroll
    for (int nt=0;nt<8;nt++){
      int h = nt*16 + l15;
      float bb = b2s[h];
      #pragma unroll
      for (int reg=0;reg<4;reg++){
        int lr = w*16 + quad*4 + reg;
        sT[lr*132 + h] = f2us(gelu_fe(acc[nt][reg] + bb));
      }
    }
  }
  __syncthreads();
  int rmax = len - r0; if (rmax > 64) rmax = 64;
  ushort4* gout = (ushort4*)(bases + (size_t)bi*16384 + r0*128);
  for (int idx = tid; idx < rmax*32; idx += 256){
    int row = idx >> 5, seg = idx & 31;
    gout[idx] = *(const ushort4*)&sT[row*132 + seg*4];
  }
}

// ---------------- message passing (R4-proven kernels) ----------------
// gs layout per layer (stride 2560): [bank0..7][sum1(128)|sq1(128)] + 2048:[sum2|sq2]

__global__ __launch_bounds__(256) void k_xwl2(const float* __restrict__ xfprev,
    const float* __restrict__ t2, const float* __restrict__ gsum2p,
    const float* __restrict__ gsq2p, const float* __restrict__ g2p,
    const float* __restrict__ bb2p, const int* __restrict__ length, int prevapply,
    const ushortt* __restrict__ wbfl, float* __restrict__ xfB,
    float* __restrict__ xfW){
  int blk = blockIdx.x;
  int b = blk >> 2, rq = blk & 3;
  int tid = threadIdx.x;
  int lane = tid & 63, w = tid >> 6, quad = lane >> 4, l15 = lane & 15;
  __shared__ alignas(16) ushortt sA[32*136];
  __shared__ float smu[128], sistd[128], sg[128], sbb[128];
  if (prevapply && tid < 128){
    float cnt = 0.f;
    for (int q2=0;q2<BB;q2++) cnt += (float)length[q2];
    float mu = gsum2p[tid]/cnt;
    float var = gsq2p[tid]/cnt - mu*mu;
    smu[tid]=mu; sistd[tid]=rsqrtf(fmaxf(var,0.0f)+EPSV);
    sg[tid]=g2p[tid]; sbb[tid]=bb2p[tid];
  }
  __syncthreads();
  for (int idx = tid; idx < 1024; idx += 256){
    int r = idx >> 5, c = idx & 31;
    int gr = b*128 + rq*32 + r;
    float4 xv = ((const float4*)xfprev)[gr*32 + c];
    if (prevapply){
      float4 tv = ((const float4*)t2)[gr*32 + c];
      int f0 = c*4;
      xv.x += fmaxf((tv.x-smu[f0+0])*sistd[f0+0]*sg[f0+0]+sbb[f0+0], 0.f);
      xv.y += fmaxf((tv.y-smu[f0+1])*sistd[f0+1]*sg[f0+1]+sbb[f0+1], 0.f);
      xv.z += fmaxf((tv.z-smu[f0+2])*sistd[f0+2]*sg[f0+2]+sbb[f0+2], 0.f);
      xv.w += fmaxf((tv.w-smu[f0+3])*sistd[f0+3]*sg[f0+3]+sbb[f0+3], 0.f);
      ((float4*)xfB)[gr*32 + c] = xv;
    }
    ushort4 o;
    o.x=f2us(xv.x); o.y=f2us(xv.y); o.z=f2us(xv.z); o.w=f2us(xv.w);
    *(ushort4*)&sA[r*136 + c*4] = o;
  }
  __syncthreads();
  f32x4 acc[2][2];
  #pragma unroll
  for (int mt=0;mt<2;mt++)
    #pragma unroll
    for (int nt=0;nt<2;nt++) acc[mt][nt] = (f32x4){0.f,0.f,0.f,0.f};
  #pragma unroll
  for (int kk = 0; kk < 128; kk += 32){
    bf16x8 af[2], bfr[2];
    #pragma unroll
    for (int mt=0;mt<2;mt++) af[mt] = *(const bf16x8*)&sA[(mt*16+l15)*136 + kk + quad*8];
    #pragma unroll
    for (int nt=0;nt<2;nt++) bfr[nt] = *(const bf16x8*)&wbfl[((w*2+nt)*16+l15)*128 + kk + quad*8];
    #pragma unroll
    for (int mt=0;mt<2;mt++)
      #pragma unroll
      for (int nt=0;nt<2;nt++)
        acc[mt][nt] = __builtin_amdgcn_mfma_f32_16x16x32_bf16(af[mt], bfr[nt], acc[mt][nt], 0, 0, 0);
  }
  #pragma unroll
  for (int mt=0;mt<2;mt++)
    #pragma unroll
    for (int nt=0;nt<2;nt++){
      int h = (w*2+nt)*16 + l15;
      #pragma unroll
      for (int reg=0;reg<4;reg++){
        int prr = rq*32 + mt*16 + quad*4 + reg;
        xfW[(b*128 + prr)*128 + h] = acc[mt][nt][reg];
      }
    }
}

// per-edge elementwise + FUSED g1 GEMM + BN1 partial stats (R4-proven)
__global__ __launch_bounds__(512) void k_edge(const float* __restrict__ xfin, float* __restrict__ xfout,
    const bf16* __restrict__ bases, const float* __restrict__ xfW,
    const float* __restrict__ bondWl, const int* __restrict__ ef,
    const int* __restrict__ length,
    const float* __restrict__ w1t, const float* __restrict__ bias1,
    float* __restrict__ t1, float* __restrict__ gst){
  int bj = blockIdx.x; int b = bj >> 7, j = bj & 127;
  int len = length[b];
  int tid = threadIdx.x; int h = tid & 127, ih = tid >> 7;   // ih in 0..3
  __shared__ float sBW[10][128];
  __shared__ int sEf[128];
  __shared__ float part[4][128];
  for (int idx = tid; idx < 1280; idx += 512) sBW[idx>>7][idx&127] = bondWl[idx];
  if (tid < 128) sEf[tid] = ef[(b*NN + tid)*NN + j];
  __syncthreads();
  float agg = 0.f;
  if (j < len){
    const float* xwb = xfW + b*NN*HH + h;
    const bf16* bb = bases + ((size_t)b*NN + j)*NN*HH + h;
    for (int i = ih; i < len; i += 4){
      float vv = gelu_h(xwb[i*128] + sBW[sEf[i]][h]);
      agg += vv * b2f(bb[i*128]);
    }
  }
  part[ih][h] = agg; __syncthreads();
  if (tid < 128){
    int o = (b*NN + j)*HH + tid;
    float xrow = xfin[o] + part[0][tid] + part[1][tid] + part[2][tid] + part[3][tid];
    xfout[o] = xrow;
    part[0][tid] = xrow;
  }
  __syncthreads();
  float acc = (ih==0) ? bias1[h] : 0.f;
  {
    const float* wcol = w1t + h;
    int m0 = ih*32;
    for (int m = m0; m < m0+32; m++) acc += part[0][m]*wcol[m*128];
  }
  float* red = &sBW[0][0];
  __syncthreads();
  red[ih*128 + h] = acc; __syncthreads();
  if (tid < 128){
    float t1v = red[tid] + red[128+tid] + red[256+tid] + red[384+tid];
    t1[(b*NN + j)*HH + tid] = t1v;
    if (j < len){
      int bank = bj & 7;
      atomicAdd(&gst[bank*256 + tid], t1v);
      atomicAdd(&gst[bank*256 + 128 + tid], t1v*t1v);
    }
  }
}

// finalize BN1 (sum 8 banks) + relu + g2 GEMM + partial BN2 stats (R4-proven)
__global__ __launch_bounds__(256) void k_g2s(const float* __restrict__ t1,
    const float* __restrict__ gstL,
    const float* __restrict__ g1, const float* __restrict__ bb1,
    const float* __restrict__ w2t, const float* __restrict__ bias2,
    const int* __restrict__ length, float* __restrict__ t2){
  int blk = blockIdx.x; int tid = threadIdx.x;
  int f = tid & 127, rh = tid >> 7;
  __shared__ float sy[4][128];
  __shared__ float red1[2][128], red2[2][128];
  int r0 = blk*4;
  float cnt = 0.f;
  for (int b=0;b<BB;b++) cnt += (float)length[b];
  float su = 0.f, sq = 0.f;
  #pragma unroll
  for (int k=0;k<8;k++){ su += gstL[k*256 + f]; sq += gstL[k*256 + 128 + f]; }
  float mu = su/cnt;
  float var = sq/cnt - mu*mu;
  float istd = rsqrtf(fmaxf(var,0.0f)+EPSV);
  float gg = g1[f], bbv = bb1[f];
  for (int idx = tid; idx < 512; idx += 256){
    int r = idx >> 7;
    float x = t1[(r0+r)*128 + f];
    float y = (x-mu)*istd*gg + bbv;
    sy[r][f] = fmaxf(y, 0.0f);
  }
  __syncthreads();
  float bsv = bias2[f];
  float s=0.f, s2=0.f;
  for (int rr = rh*2; rr < rh*2+2; rr++){
    int rg = r0 + rr; int b = rg >> 7, n = rg & 127;
    float acc = bsv;
    for (int m=0;m<128;m++) acc += sy[rr][m]*w2t[m*128+f];
    t2[rg*128+f] = acc;
    if (n < length[b]){ s += acc; s2 += acc*acc; }
  }
  red1[rh][f]=s; red2[rh][f]=s2; __syncthreads();
  if (tid < 128){
    atomicAdd((float*)&gstL[2048 + tid], red1[0][tid]+red1[1][tid]);
    atomicAdd((float*)&gstL[2048 + 128 + tid], red2[0][tid]+red2[1][tid]);
  }
}

// final BN2-apply fused into pooling + linear head (R4-proven)
__global__ void k_pool2(const float* __restrict__ xf, const float* __restrict__ t2,
                        const float* __restrict__ gsum2, const float* __restrict__ gsq2,
                        const float* __restrict__ g2, const float* __restrict__ bb2,
                        const int* __restrict__ length,
                        const float* lw, const float* lb, float* __restrict__ outp){
  int b = blockIdx.x, tid=threadIdx.x;
  int len = length[b];
  float cnt = 0.f;
  for (int q2=0;q2<BB;q2++) cnt += (float)length[q2];
  float mu = gsum2[tid]/cnt;
  float var = gsq2[tid]/cnt - mu*mu;
  float istd = rsqrtf(fmaxf(var,0.0f)+EPSV);
  float gg = g2[tid], bbv = bb2[tid];
  float s=0.f;
  for (int n2=0;n2<len;n2++){
    int o = (b*NN+n2)*HH+tid;
    float x = xf[o] + fmaxf((t2[o]-mu)*istd*gg+bbv, 0.0f);
    s += x;
  }
  s /= (float)len;
  __shared__ float red[128];
  red[tid]=s*lw[tid]; __syncthreads();
  for (int st=64;st>0;st>>=1){ if(tid<st) red[tid]+=red[tid+st]; __syncthreads(); }
  if (tid==0) outp[b]=red[0]+lb[0];
}

// ---------------- host ----------------

extern "C" void kernel_launch(void* const* d_in, const int* in_sizes, int n_in,
                              void* d_out, int out_size, void* d_ws, size_t ws_size,
                              hipStream_t stream) {
  (void)in_sizes; (void)n_in; (void)out_size; (void)ws_size;
  const float* e        = (const float*)d_in[0];
  const float* u        = (const float*)d_in[1];
  const float* atom_emb = (const float*)d_in[2];
  const float* bond_emb = (const float*)d_in[3];
  const float* eigw_W   = (const float*)d_in[4];
  const float* eigw_b   = (const float*)d_in[5];
  const float* mng      = (const float*)d_in[6];
  const float* mnb      = (const float*)d_in[7];
  const float* qkvW     = (const float*)d_in[8];
  const float* qkvb     = (const float*)d_in[9];
  const float* outW     = (const float*)d_in[10];
  const float* outb     = (const float*)d_in[11];
  const float* fng      = (const float*)d_in[12];
  const float* fnb      = (const float*)d_in[13];
  const float* ffn1W    = (const float*)d_in[14];
  const float* ffn1b    = (const float*)d_in[15];
  const float* ffn2W    = (const float*)d_in[16];
  const float* ffn2b    = (const float*)d_in[17];
  const float* decW     = (const float*)d_in[18];
  const float* decb     = (const float*)d_in[19];
  const float* fe1W     = (const float*)d_in[20];
  const float* fe1b     = (const float*)d_in[21];
  const float* fe2W     = (const float*)d_in[22];
  const float* fe2b     = (const float*)d_in[23];
  const float* preW     = (const float*)d_in[24];
  const float* preb     = (const float*)d_in[25];
  const float* f1W      = (const float*)d_in[26];
  const float* f1b      = (const float*)d_in[27];
  const float* bn1g     = (const float*)d_in[28];
  const float* bn1b     = (const float*)d_in[29];
  const float* f2W      = (const float*)d_in[30];
  const float* f2b      = (const float*)d_in[31];
  const float* bn2g     = (const float*)d_in[32];
  const float* bn2b     = (const float*)d_in[33];
  const float* linW     = (const float*)d_in[34];
  const float* linb     = (const float*)d_in[35];
  const int* nodef      = (const int*)d_in[36];
  const int* edgef      = (const int*)d_in[37];
  const int* length     = (const int*)d_in[38];

  float* outp = (float*)d_out;   // h[8] ++ new_e[4096] ++ attn[524288], f32

  char* p = (char*)d_ws;
  auto alloc = [&](size_t bytes)->void*{ void* r=(void*)p; p += (bytes+255)&~(size_t)255; return r; };
  const int TOK = BB*NN*HH;           // 131072
  float* eig   = (float*)alloc(TOK*4);
  float* q     = (float*)alloc(TOK*4);
  float* kT    = (float*)alloc(TOK*4);
  float* v     = (float*)alloc(TOK*4);
  float* newe  = (float*)alloc(BB*NHD*NN*4);
  bf16*  bases = (bf16*) alloc((size_t)BB*NN*NN*HH*2);
  float* xf0   = (float*)alloc(TOK*4);
  float* xfB   = (float*)alloc(TOK*4);
  float* xfC   = (float*)alloc(TOK*4);
  float* xfD   = (float*)alloc(TOK*4);
  float* t1    = (float*)alloc(TOK*4);
  float* t2    = (float*)alloc(TOK*4);
  float* xfW   = (float*)alloc(TOK*4);
  float* gs    = (float*)alloc(10240*4);         // 4 layers x 2560
  ushortt* wbf = (ushortt*)alloc(81920*2);
  float* eigWT = (float*)alloc(16512*4);
  float* qkvWT = (float*)alloc(49152*4);
  float* outWT = (float*)alloc(16384*4);
  float* ffn1WT= (float*)alloc(16384*4);
  float* ffn2WT= (float*)alloc(16384*4);
  float* f1WT  = (float*)alloc(65536*4);
  float* f2WT  = (float*)alloc(65536*4);
  float* bondWall = (float*)alloc(5120*4);

  k_prep<<<512, 256, 0, stream>>>(fe2W, preW, eigw_W, qkvW, outW, ffn1W, ffn2W,
                                  f1W, f2W, atom_emb, nodef, bond_emb, preb,
                                  wbf, gs, xf0, eigWT, qkvWT, outWT, ffn1WT,
                                  ffn2WT, f1WT, f2WT, bondWall);

  // front end (2 dispatches)
  k_fe_a<<<BB*NN, 128, 0, stream>>>(e, eigWT, eigw_b, mng, mnb, qkvWT, qkvb, eig, q, kT, v);
  k_attc<<<BB*NN, 512, 0, stream>>>(q, kT, v, eig, length,
                                    outWT, outb, fng, fnb,
                                    ffn1WT, ffn1b, ffn2WT, ffn2b,
                                    decW, decb, newe, outp);

  // bases (filters inlined)
  k_fe2<<<2*BB*NN, 256, 0, stream>>>(u, newe, fe1W, fe1b, wbf, fe2b, length, bases);

  // message passing: 3 kernels/layer (edge+g1 fused)
  const float* xfprev = xf0;
  float* xfcur = xfC;
  for (int l=0;l<LAY;l++){
    const ushortt* wbfl = wbf + 16384 + l*16384;
    float* gsl = gs + l*2560;
    float* gsp = gs + (l-1)*2560;
    k_xwl2<<<BB*4, 256, 0, stream>>>(xfprev, t2,
                                   (l>0)? gsp+2048 : gs, (l>0)? gsp+2048+128 : gs,
                                   bn2g + (l>0? (l-1)*HH:0), bn2b + (l>0? (l-1)*HH:0),
                                   length, (l>0)?1:0,
                                   wbfl, xfB, xfW);
    const float* xin = (l==0)? xf0 : xfB;
    k_edge<<<BB*NN, 512, 0, stream>>>(xin, xfcur, bases, xfW, bondWall + l*1280,
                                      edgef, length,
                                      f1WT + l*16384, f1b + l*HH, t1, gsl);
    k_g2s<<<256, 256, 0, stream>>>(t1, gsl, bn1g + l*HH, bn1b + l*HH,
                                   f2WT + l*16384, f2b + l*HH, length, t2);
    xfprev = xfcur;
    xfcur = (xfcur == xfC) ? xfD : xfC;
  }
  // final: BN2(layer3) applied inside pool (xfprev holds layer-3 output)
  k_pool2<<<BB, 128, 0, stream>>>(xfprev, t2, gs+3*2560+2048, gs+3*2560+2048+128,
                                  bn2g + 3*HH, bn2b + 3*HH, length, linW, linb, outp);
}